// Round 21
// baseline (62.978 us; speedup 1.0000x reference)
//
#include <hip/hip_runtime.h>

// AttentionHead: B=4, T=4096, C=1024, H=64, causal softmax(QK^T/8)V
// R21: proj15 = BARRIER-FREE proj (the attn8 lesson applied): whole W
// col-slice [48][1024] bf16 in LDS once (96KB, 1 barrier), then 8 waves
// run private 3-buffer X pipelines (fp32 gll, 2-deep prefetch, counted
// vmcnt(2), zero in-loop barriers). Every prior proj (37-53us) shared the
// per-K-step block barrier; all other fixes were neutral.
// prep_w + attn8 unchanged.

using bf16x8 = __attribute__((ext_vector_type(8))) short;
using bf16x4 = __attribute__((ext_vector_type(4))) short;
using f32x4  = __attribute__((ext_vector_type(4))) float;

#define QSCALE 0.1803368867f  // 0.125 * log2(e): softmax in exp2 domain

__device__ __forceinline__ unsigned short f2bf(float f) {
  union { float f; unsigned int u; } v; v.f = f;
  unsigned int r = v.u + 0x7fffu + ((v.u >> 16) & 1u);  // RNE
  return (unsigned short)(r >> 16);
}

__device__ __forceinline__ float fexp2(float x) {
#if __has_builtin(__builtin_amdgcn_exp2f)
  return __builtin_amdgcn_exp2f(x);
#else
  float r; asm("v_exp_f32 %0, %1" : "=v"(r) : "v"(x)); return r;
#endif
}

__device__ __forceinline__ void gl_lds16(const void* g, void* l) {
  __builtin_amdgcn_global_load_lds(
      (const __attribute__((address_space(1))) void*)g,
      (__attribute__((address_space(3))) void*)l, 16, 0, 0);
}

__device__ __forceinline__ f32x4 mfma16(bf16x4 a, bf16x4 b, f32x4 c) {
#if __has_builtin(__builtin_amdgcn_mfma_f32_16x16x16bf16_1k)
  return __builtin_amdgcn_mfma_f32_16x16x16bf16_1k(a, b, c, 0, 0, 0);
#else
  f32x4 d;
  asm volatile("v_mfma_f32_16x16x16_bf16 %0, %1, %2, %3"
               : "=v"(d) : "v"(a), "v"(b), "v"(c));
  return d;
#endif
}

// ---- prep_w: Wt[j][k] = Wsel[k][j%64] bf16 (one-time, 384KB) ----------
__global__ __launch_bounds__(256) void prep_w_kernel(
    const float* __restrict__ Wk, const float* __restrict__ Wq,
    const float* __restrict__ Wv, unsigned short* __restrict__ Wt) {
  int j = blockIdx.x;  // 0..191: [0,64)=K, [64,128)=Q, [128,192)=V
  const float* src = (j < 64) ? Wk : ((j < 128) ? Wq : Wv);
  int jj = j & 63;
  #pragma unroll
  for (int p = 0; p < 4; ++p) {
    int k = threadIdx.x + p * 256;
    Wt[j * 1024 + k] = f2bf(src[k * 64 + jj]);
  }
}

// ---- proj15: 512 blk x 512 thr; W-slice resident; barrier-free K-loop -
__global__ __launch_bounds__(512) void proj15_kernel(
    const float* __restrict__ X, const unsigned short* __restrict__ Wt,
    const float* __restrict__ bk, const float* __restrict__ bq,
    const float* __restrict__ bv, unsigned short* __restrict__ Kr,
    unsigned short* __restrict__ Qs, unsigned short* __restrict__ Vt) {
  // LDS: W-slice [48 cols][1024 k] bf16 = 96KB, + 8 waves x 3 x 2KB X bufs
  __shared__ __align__(16) char smem[147456];
  const int tid = threadIdx.x;
  const int bid = blockIdx.x;
  const int mtb = bid & 127;        // n-major: X siblings 128 apart (same XCD)
  const int nc  = bid >> 7;         // 0..3: 48-col slice
  const int w   = tid >> 6;         // wave 0..7 owns 16 rows
  const int ln  = tid & 63;
  const int l15 = ln & 15;
  const int l4  = ln >> 4;
  const int m0w = mtb * 128 + w * 16;
  const f32x4 zero4 = {0.f, 0.f, 0.f, 0.f};

  char* Wl = smem;                        // [48][128 granules of 16B]
  char* Xb = smem + 98304 + w * 6144;     // wave-private, 3 x 2KB

  // ---- one-time staging: W slice (12 gll/thread) + X steps 0,1 --------
  {
    const char* Wbase = (const char*)Wt + (size_t)nc * 48 * 2048;
    #pragma unroll
    for (int s = 0; s < 12; ++s) {
      int g = tid + s * 512;              // 0..6143
      int row = g >> 7, slot = g & 127;   // W LDS slot 'slot' of row
      gl_lds16(Wbase + (size_t)row * 2048 + ((slot ^ (row & 7)) << 4),
               Wl + g * 16);
    }
  }
  const int xrr = (ln >> 3) & 7;          // helper pieces for X staging
  auto stageX = [&](int t) {
    char* dst = Xb + (t % 3) * 2048;
    #pragma unroll
    for (int s = 0; s < 2; ++s) {
      int r = 8 * s + (ln >> 3);          // row 0..15
      int g = ln & 7;                     // slot 0..7 (granule of 4 fp32)
      gl_lds16((const char*)X + (size_t)(m0w + r) * 4096 + t * 128 +
                   ((g ^ (r & 7)) << 4),
               dst + s * 1024 + ln * 16);
    }
  };
  stageX(0);
  stageX(1);
  asm volatile("s_waitcnt vmcnt(0)" ::: "memory");
  __syncthreads();                        // W + first X tiles resident

  f32x4 acc[3];
  #pragma unroll
  for (int i = 0; i < 3; ++i) acc[i] = zero4;

  const int rs7 = l15 & 7;                // A-frag row swizzle key
  for (int t = 0; t < 32; ++t) {          // K steps of 32 (NO barriers)
    const bool pf = (t + 2 < 32);
    if (pf) stageX(t + 2);                // 2-deep private prefetch
    // A-fragment: 8 fp32 from private swizzled Xbuf -> bf16
    const char* xp = Xb + (t % 3) * 2048 + l15 * 128;
    f32x4 xa0 = *reinterpret_cast<const f32x4*>(xp + (((2 * l4)     ^ rs7) << 4));
    f32x4 xa1 = *reinterpret_cast<const f32x4*>(xp + (((2 * l4 + 1) ^ rs7) << 4));
    bf16x8 a0;
    #pragma unroll
    for (int i = 0; i < 4; ++i) {
      a0[i]     = (short)f2bf(xa0[i]);
      a0[4 + i] = (short)f2bf(xa1[i]);
    }
    // B-fragments from resident W slice (read-only, swizzled)
    #pragma unroll
    for (int i = 0; i < 3; ++i) {
      const int j = i * 16 + l15;
      bf16x8 b0 = *reinterpret_cast<const bf16x8*>(
          Wl + j * 2048 + (((4 * t + l4) ^ (j & 7)) << 4));
      acc[i] = __builtin_amdgcn_mfma_f32_16x16x32_bf16(a0, b0, acc[i], 0, 0, 0);
    }
    if (pf)           asm volatile("s_waitcnt vmcnt(2)" ::: "memory");
    else if (t < 31)  asm volatile("s_waitcnt vmcnt(0)" ::: "memory");
    __builtin_amdgcn_sched_barrier(0);
  }

  // ---- epilogue: bias + store ----------------------------------------
  #pragma unroll
  for (int i = 0; i < 3; ++i) {
    int j   = nc * 48 + i * 16 + l15;     // global output col (0..191)
    int mr0 = m0w + l4 * 4;
    if (j < 64) {
      #pragma unroll
      for (int r = 0; r < 4; ++r)
        Kr[(size_t)(mr0 + r) * 64 + j] = f2bf(acc[i][r] + bk[j]);
    } else if (j < 128) {
      int jq = j - 64;
      #pragma unroll
      for (int r = 0; r < 4; ++r)
        Qs[(size_t)(mr0 + r) * 64 + jq] = f2bf((acc[i][r] + bq[jq]) * QSCALE);
    } else {
      int h = j - 128;
      int bb = mr0 >> 12, t0 = mr0 & 4095;
      ushort4 o;
      o.x = f2bf(acc[i][0] + bv[h]); o.y = f2bf(acc[i][1] + bv[h]);
      o.z = f2bf(acc[i][2] + bv[h]); o.w = f2bf(acc[i][3] + bv[h]);
      *reinterpret_cast<ushort4*>(&Vt[((size_t)(bb * 64 + h)) * 4096 + t0]) = o;
    }
  }
  (void)xrr;
}

// ---- attn8: paired q-tiles, 8 waves, kv-split-8, no in-loop barriers --
__global__ __launch_bounds__(512) void attn8_kernel(
    const unsigned short* __restrict__ Qs,
    const unsigned short* __restrict__ Kr,
    const unsigned short* __restrict__ Vt,
    float* __restrict__ out) {
  __shared__ __align__(16) char smem[98304];   // 96KB: 8 waves x 12KB
  const int tid = threadIdx.x;
  const int w   = tid >> 6;            // 0..7: kv residue class
  const int ln  = tid & 63;
  const int l15 = ln & 15;
  const int l4  = ln >> 4;
  const int bid = blockIdx.x;          // 0..255
  const int pr  = bid >> 2;            // 0..63: q-tile pair index
  const int b   = bid & 3;             // batch pinned per XCD
  const f32x4 zero4 = {0.f, 0.f, 0.f, 0.f};

  char* Kl = smem + w * 12288;         // 2 x 4KB K dbuf
  char* Vl = Kl + 8192;                // 4KB V

  const int kLane = (ln >> 3) * 128 + ((ln & 7) ^ (ln >> 3)) * 16;
  const int vLane = (ln >> 2) * 8192 + (((ln & 3) ^ ((ln >> 3) & 3))) * 16;
  const char* Kbase = (const char*)Kr + (size_t)b * 4096 * 128;
  const char* Vbase = (const char*)Vt + (size_t)b * 64 * 8192;

  auto phase = [&](int qt, bool entryBar) {
    if (entryBar) __syncthreads();     // protect staging LDS vs prior merge
    const int qbase  = qt * 32;
    const int ntiles = qt + 1;         // 32-wide kv tiles

    const unsigned short* Q0 = Qs + ((size_t)b * 4096 + qbase + l15) * 64;
    const bf16x8 qa0 = *reinterpret_cast<const bf16x8*>(Q0 + l4 * 8);
    const bf16x8 qa1 = *reinterpret_cast<const bf16x8*>(Q0 + 32 + l4 * 8);
    const bf16x8 qb0 = *reinterpret_cast<const bf16x8*>(Q0 + 1024 + l4 * 8);
    const bf16x8 qb1 = *reinterpret_cast<const bf16x8*>(Q0 + 1024 + 32 + l4 * 8);

    f32x4 accA[4], accB[4];
    #pragma unroll
    for (int i = 0; i < 4; ++i) { accA[i] = zero4; accB[i] = zero4; }
    float mA = -1e30f, lA = 0.f, mB = -1e30f, lB = 0.f;

    auto stageK = [&](int buf, int t) {
      const char* src = Kbase + (size_t)t * 4096;
      char* dst = Kl + buf * 4096;
      #pragma unroll
      for (int c = 0; c < 4; ++c)
        gl_lds16(src + c * 1024 + kLane, dst + c * 1024 + ln * 16);
    };
    auto stageV = [&](int t) {
      const char* src = Vbase + (size_t)t * 64;
      #pragma unroll
      for (int c = 0; c < 4; ++c)
        gl_lds16(src + (size_t)c * 16 * 8192 + vLane, Vl + c * 1024 + ln * 16);
    };

    int cur = 0;
    if (w < ntiles) stageK(0, w);

    for (int t = w; t < ntiles; t += 8) {
      stageV(t);
      const bool hn = (t + 8 < ntiles);
      if (hn) stageK(cur ^ 1, t + 8);

      if (hn) asm volatile("s_waitcnt vmcnt(8)" ::: "memory");
      else    asm volatile("s_waitcnt vmcnt(4)" ::: "memory");
      __builtin_amdgcn_sched_barrier(0);

      // S^T = K Q^T : s[nt][r] = S[kv=nt*16+4*l4+r][q=l15]
      f32x4 sA[2], sB[2];
      #pragma unroll
      for (int i = 0; i < 2; ++i) { sA[i] = zero4; sB[i] = zero4; }
      __builtin_amdgcn_s_setprio(1);
      #pragma unroll
      for (int nt = 0; nt < 2; ++nt) {
        const int krow = nt * 16 + l15;
        const unsigned short* kp =
            (const unsigned short*)(Kl + cur * 4096) + krow * 64;
        bf16x8 k0 = *reinterpret_cast<const bf16x8*>(kp + ((l4 ^ (krow & 7)) << 3));
        bf16x8 k1 = *reinterpret_cast<const bf16x8*>(kp + (((l4 + 4) ^ (krow & 7)) << 3));
        sA[nt] = __builtin_amdgcn_mfma_f32_16x16x32_bf16(k0, qa0, sA[nt], 0, 0, 0);
        sA[nt] = __builtin_amdgcn_mfma_f32_16x16x32_bf16(k1, qa1, sA[nt], 0, 0, 0);
        sB[nt] = __builtin_amdgcn_mfma_f32_16x16x32_bf16(k0, qb0, sB[nt], 0, 0, 0);
        sB[nt] = __builtin_amdgcn_mfma_f32_16x16x32_bf16(k1, qb1, sB[nt], 0, 0, 0);
      }
      __builtin_amdgcn_s_setprio(0);

      if (t == ntiles - 1) {  // diagonal tile
        const int qm = qbase + l15 - t * 32;
        #pragma unroll
        for (int nt = 0; nt < 2; ++nt)
          #pragma unroll
          for (int r = 0; r < 4; ++r) {
            int kvl = nt * 16 + 4 * l4 + r;
            if (kvl > qm)      sA[nt][r] = -1e30f;
            if (kvl > qm + 16) sB[nt][r] = -1e30f;
          }
      }

      bf16x4 paA[2], paB[2];
      {
        float x0 = fmaxf(fmaxf(sA[0][0], sA[0][1]), fmaxf(sA[0][2], sA[0][3]));
        float x1 = fmaxf(fmaxf(sA[1][0], sA[1][1]), fmaxf(sA[1][2], sA[1][3]));
        float xm = fmaxf(x0, x1);
        xm = fmaxf(xm, __shfl_xor(xm, 16));
        xm = fmaxf(xm, __shfl_xor(xm, 32));
        float mn = fmaxf(mA, xm);
        float cc = fexp2(mA - mn);
        mA = mn; lA *= cc;
        #pragma unroll
        for (int ht = 0; ht < 4; ++ht)
          #pragma unroll
          for (int r = 0; r < 4; ++r) accA[ht][r] *= cc;
        float sum = 0.f;
        #pragma unroll
        for (int nt = 0; nt < 2; ++nt) {
          #pragma unroll
          for (int r = 0; r < 4; ++r) {
            float p = fexp2(sA[nt][r] - mA);
            sA[nt][r] = p;
            paA[nt][r] = (short)f2bf(p);
          }
          sum += (sA[nt][0] + sA[nt][1]) + (sA[nt][2] + sA[nt][3]);
        }
        sum += __shfl_xor(sum, 16);
        sum += __shfl_xor(sum, 32);
        lA += sum;
      }
      {
        float x0 = fmaxf(fmaxf(sB[0][0], sB[0][1]), fmaxf(sB[0][2], sB[0][3]));
        float x1 = fmaxf(fmaxf(sB[1][0], sB[1][1]), fmaxf(sB[1][2], sB[1][3]));
        float xm = fmaxf(x0, x1);
        xm = fmaxf(xm, __shfl_xor(xm, 16));
        xm = fmaxf(xm, __shfl_xor(xm, 32));
        float mn = fmaxf(mB, xm);
        float cc = fexp2(mB - mn);
        mB = mn; lB *= cc;
        #pragma unroll
        for (int ht = 0; ht < 4; ++ht)
          #pragma unroll
          for (int r = 0; r < 4; ++r) accB[ht][r] *= cc;
        float sum = 0.f;
        #pragma unroll
        for (int nt = 0; nt < 2; ++nt) {
          #pragma unroll
          for (int r = 0; r < 4; ++r) {
            float p = fexp2(sB[nt][r] - mB);
            sB[nt][r] = p;
            paB[nt][r] = (short)f2bf(p);
          }
          sum += (sB[nt][0] + sB[nt][1]) + (sB[nt][2] + sB[nt][3]);
        }
        sum += __shfl_xor(sum, 16);
        sum += __shfl_xor(sum, 32);
        lB += sum;
      }

      if (hn) asm volatile("s_waitcnt vmcnt(4)" ::: "memory");
      else    asm volatile("s_waitcnt vmcnt(0)" ::: "memory");
      __builtin_amdgcn_sched_barrier(0);

      // O^T += V^T P^T
      __builtin_amdgcn_s_setprio(1);
      #pragma unroll
      for (int nt = 0; nt < 2; ++nt) {
        #pragma unroll
        for (int ht = 0; ht < 4; ++ht) {
          const int vrow = ht * 16 + l15;
          const int g16 = (nt * 2 + (l4 >> 1)) ^ ((vrow >> 1) & 3);
          const char* vp = Vl + vrow * 64 + (g16 << 4) + ((l4 & 1) << 3);
          bf16x4 vf = *reinterpret_cast<const bf16x4*>(vp);
          accA[ht] = mfma16(vf, paA[nt], accA[ht]);
          accB[ht] = mfma16(vf, paB[nt], accB[ht]);
        }
      }
      __builtin_amdgcn_s_setprio(0);
      cur ^= 1;
    }

    // ---- exact 8-way merge, distributed across all 512 threads -------
    __syncthreads();
    float* MO = (float*)smem;                   // [8][2][16][68] = 68KB
    float* ML = (float*)(smem + 8 * 2 * 16 * 68 * 4);  // [8][2][2][16]
    #pragma unroll
    for (int ht = 0; ht < 4; ++ht) {
      *reinterpret_cast<f32x4*>(&MO[((w * 2 + 0) * 16 + l15) * 68 + ht * 16 + 4 * l4]) = accA[ht];
      *reinterpret_cast<f32x4*>(&MO[((w * 2 + 1) * 16 + l15) * 68 + ht * 16 + 4 * l4]) = accB[ht];
    }
    if (l4 == 0) {
      ML[((w * 2 + 0) * 2 + 0) * 16 + l15] = mA;
      ML[((w * 2 + 0) * 2 + 1) * 16 + l15] = lA;
      ML[((w * 2 + 1) * 2 + 0) * 16 + l15] = mB;
      ML[((w * 2 + 1) * 2 + 1) * 16 + l15] = lB;
    }
    __syncthreads();
    {
      const int hf = tid >> 8;        // 0..1 (q-half)
      const int q  = (tid >> 4) & 15;
      const int hq = tid & 15;        // h-quad
      float mv[8], lv[8];
      float mM = -1e30f;
      #pragma unroll
      for (int p = 0; p < 8; ++p) {
        mv[p] = ML[((p * 2 + hf) * 2 + 0) * 16 + q];
        lv[p] = ML[((p * 2 + hf) * 2 + 1) * 16 + q];
        mM = fmaxf(mM, mv[p]);
      }
      float lT = 0.f, a[8];
      #pragma unroll
      for (int p = 0; p < 8; ++p) { a[p] = fexp2(mv[p] - mM); lT += lv[p] * a[p]; }
      float linv = 1.0f / lT;
      f32x4 o = zero4;
      #pragma unroll
      for (int p = 0; p < 8; ++p) {
        f32x4 v = *reinterpret_cast<const f32x4*>(
            &MO[((p * 2 + hf) * 16 + q) * 68 + hq * 4]);
        o[0] += v[0] * a[p]; o[1] += v[1] * a[p];
        o[2] += v[2] * a[p]; o[3] += v[3] * a[p];
      }
      float4 ov;
      ov.x = o[0] * linv; ov.y = o[1] * linv;
      ov.z = o[2] * linv; ov.w = o[3] * linv;
      *reinterpret_cast<float4*>(
          out + ((size_t)b * 4096 + qbase + hf * 16 + q) * 64 + hq * 4) = ov;
    }
  };

  phase(127 - pr, false);   // big q-tile first
  phase(pr, true);          // complement: total work ~equal for all blocks
}

// ---- Plan-B fallback (ws too small): proj no-Q + attn recompute-Q -----
template <bool WRITE_Q>
__global__ __launch_bounds__(256) void proj_kernel(
    const float* __restrict__ X,  const float* __restrict__ Wk,
    const float* __restrict__ Wq, const float* __restrict__ Wv,
    const float* __restrict__ bk, const float* __restrict__ bq,
    const float* __restrict__ bv, unsigned short* __restrict__ Kr,
    unsigned short* __restrict__ Qs, unsigned short* __restrict__ Vt) {
  constexpr int NT = WRITE_Q ? 12 : 8;
  constexpr int NC = NT / 4;
  __shared__ __align__(16) unsigned short Xl[64 * 72];
  __shared__ __align__(16) unsigned short Wl[NT * 16 * 72];
  const int tid = threadIdx.x;
  const int m0  = blockIdx.x * 64;
  const int w   = tid >> 6;
  const int ln  = tid & 63;
  const int l15 = ln & 15;
  const int l4  = ln >> 4;
  const f32x4 zero4 = {0.f, 0.f, 0.f, 0.f};
  f32x4 acc[NT];
  #pragma unroll
  for (int i = 0; i < NT; ++i) acc[i] = zero4;
  const int wn = tid & 63;
  const int wk = (tid >> 6) * 16;
  for (int kb = 0; kb < 16; ++kb) {
    __syncthreads();
    #pragma unroll
    for (int p = 0; p < 4; ++p) {
      int chunk = tid + p * 256;
      int r = chunk >> 4, c4 = chunk & 15;
      const float4 xv = *reinterpret_cast<const float4*>(
          X + (size_t)(m0 + r) * 1024 + kb * 64 + c4 * 4);
      bf16x4 o;
      o[0] = (short)f2bf(xv.x); o[1] = (short)f2bf(xv.y);
      o[2] = (short)f2bf(xv.z); o[3] = (short)f2bf(xv.w);
      *reinterpret_cast<bf16x4*>(&Xl[r * 72 + c4 * 4]) = o;
    }
    #pragma unroll
    for (int c = 0; c < NC; ++c) {
      const float* Wsrc = (c == 0) ? Wk : ((WRITE_Q && c == 1) ? Wq : Wv);
      bf16x8 w0, w1;
      #pragma unroll
      for (int j = 0; j < 8; ++j)
        w0[j] = (short)f2bf(Wsrc[(size_t)(kb * 64 + wk + j) * 64 + wn]);
      #pragma unroll
      for (int j = 0; j < 8; ++j)
        w1[j] = (short)f2bf(Wsrc[(size_t)(kb * 64 + wk + 8 + j) * 64 + wn]);
      *reinterpret_cast<bf16x8*>(&Wl[(c * 64 + wn) * 72 + wk])     = w0;
      *reinterpret_cast<bf16x8*>(&Wl[(c * 64 + wn) * 72 + wk + 8]) = w1;
    }
    __syncthreads();
    bf16x8 a0 = *reinterpret_cast<const bf16x8*>(&Xl[(w * 16 + l15) * 72 + l4 * 8]);
    bf16x8 a1 = *reinterpret_cast<const bf16x8*>(&Xl[(w * 16 + l15) * 72 + 32 + l4 * 8]);
    #pragma unroll
    for (int nt = 0; nt < NT; ++nt) {
      bf16x8 b0 = *reinterpret_cast<const bf16x8*>(&Wl[(nt * 16 + l15) * 72 + l4 * 8]);
      bf16x8 b1 = *reinterpret_cast<const bf16x8*>(&Wl[(nt * 16 + l15) * 72 + 32 + l4 * 8]);
      acc[nt] = __builtin_amdgcn_mfma_f32_16x16x32_bf16(a0, b0, acc[nt], 0, 0, 0);
      acc[nt] = __builtin_amdgcn_mfma_f32_16x16x32_bf16(a1, b1, acc[nt], 0, 0, 0);
    }
  }
  #pragma unroll
  for (int nt = 0; nt < NT; ++nt) {
    int j = nt * 16 + l15;
    #pragma unroll
    for (int r = 0; r < 4; ++r) {
      int m = m0 + w * 16 + l4 * 4 + r;
      float v = acc[nt][r];
      if (nt < 4) {
        Kr[(size_t)m * 64 + j] = f2bf(v + bk[j]);
      } else if (WRITE_Q && nt < 8) {
        Qs[(size_t)m * 64 + (j - 64)] = f2bf((v + bq[j - 64]) * QSCALE);
      } else {
        int h = j - (WRITE_Q ? 128 : 64);
        int bb = m >> 12, t = m & 4095;
        Vt[((size_t)(bb * 64 + h)) * 4096 + t] = f2bf(v + bv[h]);
      }
    }
  }
}

__global__ __launch_bounds__(256) void attnB_kernel(
    const unsigned short* __restrict__ Kr,
    const unsigned short* __restrict__ Vt,
    const float* __restrict__ X, const float* __restrict__ Wq,
    const float* __restrict__ bq, float* __restrict__ out) {
  __shared__ __align__(16) unsigned short Kl[64 * 72];
  __shared__ __align__(16) unsigned short Vl[64 * 72];
  __shared__ __align__(16) unsigned short Pl[4 * 16 * 72];
  const int tid = threadIdx.x;
  const int w   = tid >> 6;
  const int ln  = tid & 63;
  const int l15 = ln & 15;
  const int l4  = ln >> 4;
  const int b   = blockIdx.y;
  const int q0  = blockIdx.x * 64;
  const int qrow = q0 + w * 16;
  const f32x4 zero4 = {0.f, 0.f, 0.f, 0.f};
  unsigned short* Pw = &Pl[w * 16 * 72];
  f32x4 accq[4];
  #pragma unroll
  for (int i = 0; i < 4; ++i) accq[i] = zero4;
  const int wn = tid & 63;
  const int wk = (tid >> 6) * 16;
  for (int kb = 0; kb < 16; ++kb) {
    __syncthreads();
    #pragma unroll
    for (int p = 0; p < 4; ++p) {
      int chunk = tid + p * 256;
      int r = chunk >> 4, c4 = chunk & 15;
      const float4 xv = *reinterpret_cast<const float4*>(
          X + ((size_t)b * 4096 + q0 + r) * 1024 + kb * 64 + c4 * 4);
      bf16x4 o;
      o[0] = (short)f2bf(xv.x); o[1] = (short)f2bf(xv.y);
      o[2] = (short)f2bf(xv.z); o[3] = (short)f2bf(xv.w);
      *reinterpret_cast<bf16x4*>(&Kl[r * 72 + c4 * 4]) = o;
    }
    bf16x8 w0, w1;
    #pragma unroll
    for (int j = 0; j < 8; ++j)
      w0[j] = (short)f2bf(Wq[(size_t)(kb * 64 + wk + j) * 64 + wn]);
    #pragma unroll
    for (int j = 0; j < 8; ++j)
      w1[j] = (short)f2bf(Wq[(size_t)(kb * 64 + wk + 8 + j) * 64 + wn]);
    *reinterpret_cast<bf16x8*>(&Vl[wn * 72 + wk])     = w0;
    *reinterpret_cast<bf16x8*>(&Vl[wn * 72 + wk + 8]) = w1;
    __syncthreads();
    bf16x8 a0 = *reinterpret_cast<const bf16x8*>(&Kl[(w * 16 + l15) * 72 + l4 * 8]);
    bf16x8 a1 = *reinterpret_cast<const bf16x8*>(&Kl[(w * 16 + l15) * 72 + 32 + l4 * 8]);
    #pragma unroll
    for (int nt = 0; nt < 4; ++nt) {
      bf16x8 b0 = *reinterpret_cast<const bf16x8*>(&Vl[(nt * 16 + l15) * 72 + l4 * 8]);
      bf16x8 b1 = *reinterpret_cast<const bf16x8*>(&Vl[(nt * 16 + l15) * 72 + 32 + l4 * 8]);
      accq[nt] = __builtin_amdgcn_mfma_f32_16x16x32_bf16(a0, b0, accq[nt], 0, 0, 0);
      accq[nt] = __builtin_amdgcn_mfma_f32_16x16x32_bf16(a1, b1, accq[nt], 0, 0, 0);
    }
  }
  #pragma unroll
  for (int nt = 0; nt < 4; ++nt) {
    int h = nt * 16 + l15;
    #pragma unroll
    for (int r = 0; r < 4; ++r)
      Pw[(l4 * 4 + r) * 72 + h] = f2bf((accq[nt][r] + bq[h]) * 0.125f);
  }
  asm volatile("s_waitcnt lgkmcnt(0)" ::: "memory");
  __builtin_amdgcn_sched_barrier(0);
  bf16x8 qa0 = *reinterpret_cast<const bf16x8*>(&Pw[l15 * 72 + l4 * 8]);
  bf16x8 qa1 = *reinterpret_cast<const bf16x8*>(&Pw[l15 * 72 + 32 + l4 * 8]);
  f32x4 acco[4];
  #pragma unroll
  for (int i = 0; i < 4; ++i) acco[i] = zero4;
  float mrow[4] = {-1e30f, -1e30f, -1e30f, -1e30f};
  float lrow[4] = {0.f, 0.f, 0.f, 0.f};
  const int ktmax = blockIdx.x;
  for (int kt = 0; kt <= ktmax; ++kt) {
    const int kv0 = kt * 64;
    __syncthreads();
    #pragma unroll
    for (int p = 0; p < 2; ++p) {
      int chunk = tid + p * 256;
      int r = chunk >> 3, c8 = chunk & 7;
      *reinterpret_cast<bf16x8*>(&Kl[r * 72 + c8 * 8]) =
          *reinterpret_cast<const bf16x8*>(Kr + ((size_t)b * 4096 + kv0 + r) * 64 + c8 * 8);
      *reinterpret_cast<bf16x8*>(&Vl[r * 72 + c8 * 8]) =
          *reinterpret_cast<const bf16x8*>(Vt + ((size_t)b * 64 + r) * 4096 + kv0 + c8 * 8);
    }
    __syncthreads();
    f32x4 s[4];
    #pragma unroll
    for (int i = 0; i < 4; ++i) s[i] = zero4;
    #pragma unroll
    for (int nt = 0; nt < 4; ++nt) {
      bf16x8 k0 = *reinterpret_cast<const bf16x8*>(&Kl[(nt * 16 + l15) * 72 + l4 * 8]);
      bf16x8 k1 = *reinterpret_cast<const bf16x8*>(&Kl[(nt * 16 + l15) * 72 + 32 + l4 * 8]);
      s[nt] = __builtin_amdgcn_mfma_f32_16x16x32_bf16(qa0, k0, s[nt], 0, 0, 0);
      s[nt] = __builtin_amdgcn_mfma_f32_16x16x32_bf16(qa1, k1, s[nt], 0, 0, 0);
    }
    if (kt == ktmax) {
      #pragma unroll
      for (int nt = 0; nt < 4; ++nt) {
        int kv_g = kv0 + nt * 16 + l15;
        #pragma unroll
        for (int r = 0; r < 4; ++r) {
          int q_g = qrow + l4 * 4 + r;
          if (kv_g > q_g) s[nt][r] = -1e30f;
        }
      }
    }
    #pragma unroll
    for (int r = 0; r < 4; ++r) {
      float t = fmaxf(fmaxf(s[0][r], s[1][r]), fmaxf(s[2][r], s[3][r]));
      t = fmaxf(t, __shfl_xor(t, 1));
      t = fmaxf(t, __shfl_xor(t, 2));
      t = fmaxf(t, __shfl_xor(t, 4));
      t = fmaxf(t, __shfl_xor(t, 8));
      float mnew = fmaxf(mrow[r], t);
      float cc = __expf(mrow[r] - mnew);
      mrow[r] = mnew;
      lrow[r] *= cc;
      acco[0][r] *= cc; acco[1][r] *= cc; acco[2][r] *= cc; acco[3][r] *= cc;
    }
    #pragma unroll
    for (int nt = 0; nt < 4; ++nt) {
      #pragma unroll
      for (int r = 0; r < 4; ++r) {
        float p = __expf(s[nt][r] - mrow[r]);
        s[nt][r] = p;
        Pw[(l4 * 4 + r) * 72 + nt * 16 + l15] = f2bf(p);
      }
    }
    #pragma unroll
    for (int r = 0; r < 4; ++r) {
      float t = s[0][r] + s[1][r] + s[2][r] + s[3][r];
      t += __shfl_xor(t, 1);
      t += __shfl_xor(t, 2);
      t += __shfl_xor(t, 4);
      t += __shfl_xor(t, 8);
      lrow[r] += t;
    }
    asm volatile("s_waitcnt lgkmcnt(0)" ::: "memory");
    __builtin_amdgcn_sched_barrier(0);
    #pragma unroll
    for (int ks = 0; ks < 2; ++ks) {
      bf16x8 pa = *reinterpret_cast<const bf16x8*>(&Pw[l15 * 72 + ks * 32 + l4 * 8]);
      #pragma unroll
      for (int ht = 0; ht < 4; ++ht) {
        bf16x8 vf = *reinterpret_cast<const bf16x8*>(&Vl[(ht * 16 + l15) * 72 + ks * 32 + l4 * 8]);
        acco[ht] = __builtin_amdgcn_mfma_f32_16x16x32_bf16(pa, vf, acco[ht], 0, 0, 0);
      }
    }
  }
  float* ob = out + ((size_t)b * 4096 + qrow) * 64;
  #pragma unroll
  for (int ht = 0; ht < 4; ++ht) {
    #pragma unroll
    for (int r = 0; r < 4; ++r) {
      ob[(l4 * 4 + r) * 64 + ht * 16 + l15] = acco[ht][r] / lrow[r];
    }
  }
}

extern "C" void kernel_launch(void* const* d_in, const int* in_sizes, int n_in,
                              void* d_out, int out_size, void* d_ws, size_t ws_size,
                              hipStream_t stream) {
  const float* X  = (const float*)d_in[0];
  const float* Wk = (const float*)d_in[1];
  const float* bk = (const float*)d_in[2];
  const float* Wq = (const float*)d_in[3];
  const float* bq = (const float*)d_in[4];
  const float* Wv = (const float*)d_in[5];
  const float* bv = (const float*)d_in[6];
  float* out = (float*)d_out;

  char* ws = (char*)d_ws;
  const size_t SZ = 2097152;   // one bf16 [B*T][64] buffer
  const size_t WT = 393216;    // Wt bf16[192][1024]
  unsigned short* Kr = (unsigned short*)(ws);
  unsigned short* Vt = (unsigned short*)(ws + SZ);

  if (ws_size >= 3 * SZ) {
    unsigned short* Qs = (unsigned short*)(ws + 2 * SZ);
    // Wt scratch: ws tail if it fits, else head of d_out (attn8 rewrites
    // all of out afterwards on the same stream -> deterministic).
    unsigned short* Wt = (ws_size >= 3 * SZ + WT)
                             ? (unsigned short*)(ws + 3 * SZ)
                             : (unsigned short*)d_out;
    prep_w_kernel<<<192, 256, 0, stream>>>(Wk, Wq, Wv, Wt);
    proj15_kernel<<<512, 512, 0, stream>>>(X, Wt, bk, bq, bv, Kr, Qs, Vt);
    attn8_kernel<<<256, 512, 0, stream>>>(Qs, Kr, Vt, out);
  } else {
    proj_kernel<false><<<256, 256, 0, stream>>>(X, Wk, Wq, Wv, bk, bq, bv, Kr, nullptr, Vt);
    attnB_kernel<<<dim3(64, 4), 256, 0, stream>>>(Kr, Vt, X, Wq, bq, out);
  }
}

// Round 22
// 62.301 us; speedup vs baseline: 1.0109x; 1.0109x over previous
//
#include <hip/hip_runtime.h>

// AttentionHead: B=4, T=4096, C=1024, H=64, causal softmax(QK^T/8)V
// R22: proj20 = DEMAND-MINIMIZED proj. Unified model from 8 proj variants:
// dur ~= (X + W + write demand)/7TB/s composite. Lever: W restage = blocks
// x 384KB. 256 blocks x 64 rows halves W demand vs proj8/13 (192->96MB).
// Geometry proj4 + Wt-bf16 gll (proj8) + convert-at-stage X (proj11).
// prep_w + attn8 unchanged.

using bf16x8 = __attribute__((ext_vector_type(8))) short;
using bf16x4 = __attribute__((ext_vector_type(4))) short;
using f32x4  = __attribute__((ext_vector_type(4))) float;

#define QSCALE 0.1803368867f  // 0.125 * log2(e): softmax in exp2 domain

__device__ __forceinline__ unsigned short f2bf(float f) {
  union { float f; unsigned int u; } v; v.f = f;
  unsigned int r = v.u + 0x7fffu + ((v.u >> 16) & 1u);  // RNE
  return (unsigned short)(r >> 16);
}

__device__ __forceinline__ float fexp2(float x) {
#if __has_builtin(__builtin_amdgcn_exp2f)
  return __builtin_amdgcn_exp2f(x);
#else
  float r; asm("v_exp_f32 %0, %1" : "=v"(r) : "v"(x)); return r;
#endif
}

__device__ __forceinline__ void gl_lds16(const void* g, void* l) {
  __builtin_amdgcn_global_load_lds(
      (const __attribute__((address_space(1))) void*)g,
      (__attribute__((address_space(3))) void*)l, 16, 0, 0);
}

__device__ __forceinline__ f32x4 mfma16(bf16x4 a, bf16x4 b, f32x4 c) {
#if __has_builtin(__builtin_amdgcn_mfma_f32_16x16x16bf16_1k)
  return __builtin_amdgcn_mfma_f32_16x16x16bf16_1k(a, b, c, 0, 0, 0);
#else
  f32x4 d;
  asm volatile("v_mfma_f32_16x16x16_bf16 %0, %1, %2, %3"
               : "=v"(d) : "v"(a), "v"(b), "v"(c));
  return d;
#endif
}

// ---- prep_w: Wt[j][k] = Wsel[k][j%64] bf16 (one-time, 384KB) ----------
__global__ __launch_bounds__(256) void prep_w_kernel(
    const float* __restrict__ Wk, const float* __restrict__ Wq,
    const float* __restrict__ Wv, unsigned short* __restrict__ Wt) {
  int j = blockIdx.x;  // 0..191: [0,64)=K, [64,128)=Q, [128,192)=V
  const float* src = (j < 64) ? Wk : ((j < 128) ? Wq : Wv);
  int jj = j & 63;
  #pragma unroll
  for (int p = 0; p < 4; ++p) {
    int k = threadIdx.x + p * 256;
    Wt[j * 1024 + k] = f2bf(src[k * 64 + jj]);
  }
}

// ---- proj20: 256 blocks x 512 thr; 64 rows x 192 cols; 64KB LDS -------
__global__ __launch_bounds__(512) void proj20_kernel(
    const float* __restrict__ X, const unsigned short* __restrict__ Wt,
    const float* __restrict__ bk, const float* __restrict__ bq,
    const float* __restrict__ bv, unsigned short* __restrict__ Kr,
    unsigned short* __restrict__ Qs, unsigned short* __restrict__ Vt) {
  __shared__ __align__(16) unsigned short Xl[2][64 * 64];   // 16 KB bf16
  __shared__ __align__(16) unsigned short Wl[2][192 * 64];  // 48 KB bf16
  const int tid = threadIdx.x;
  const int m0  = blockIdx.x * 64;
  const int w   = tid >> 6;      // 0..7
  const int mt  = w & 3;         // 16-row tile
  const int nh  = w >> 2;        // 96-col half
  const int ln  = tid & 63;
  const int l15 = ln & 15;
  const int l4  = ln >> 4;
  const f32x4 zero4 = {0.f, 0.f, 0.f, 0.f};

  // X: thread loads 2 float4 at row xr (0..63), cols xseg*8 + {0,4} of the
  // 64-col chunk; converts to one bf16x8 granule; writes at swizzled slot
  // xseg^(xr&7) of the row's 128B (both-sides swizzle, rule #21).
  const int xr = tid >> 3, xseg = tid & 7;
  const float* Xsrc = X + (size_t)(m0 + xr) * 1024 + xseg * 8;
  const int xws = xr * 128 + ((xseg ^ (xr & 7)) << 4);
  // W gll: 3 granules/thread; g=tid+s*512, row=g>>3 (0..191), slot g&7 holds
  // source granule (g&7)^(row&7). Wt row stride 2048B.
  const char* Wb = (const char*)Wt;

  f32x4 acc[6];
  #pragma unroll
  for (int i = 0; i < 6; ++i) acc[i] = zero4;

  auto stageW = [&](int buf, int kb) {
    #pragma unroll
    for (int s = 0; s < 3; ++s) {
      int g = tid + s * 512;
      int row = g >> 3, gc = g & 7;
      gl_lds16(Wb + (size_t)row * 2048 + kb * 128 + ((gc ^ (row & 7)) << 4),
               (char*)&Wl[buf][0] + g * 16);
    }
  };
  auto writeX = [&](int buf, float4 xv0, float4 xv1) {
    bf16x8 o;
    o[0] = (short)f2bf(xv0.x); o[1] = (short)f2bf(xv0.y);
    o[2] = (short)f2bf(xv0.z); o[3] = (short)f2bf(xv0.w);
    o[4] = (short)f2bf(xv1.x); o[5] = (short)f2bf(xv1.y);
    o[6] = (short)f2bf(xv1.z); o[7] = (short)f2bf(xv1.w);
    *reinterpret_cast<bf16x8*>((char*)&Xl[buf][0] + xws) = o;
  };

  float4 xc0 = *reinterpret_cast<const float4*>(Xsrc);
  float4 xc1 = *reinterpret_cast<const float4*>(Xsrc + 4);
  writeX(0, xc0, xc1);
  stageW(0, 0);
  asm volatile("s_waitcnt vmcnt(0)" ::: "memory");
  __syncthreads();

  const int rr  = mt * 16 + l15;  // X fragment row (0..63)
  const int rs7 = rr & 7;
  for (int kb = 0; kb < 16; ++kb) {
    const int buf = kb & 1;
    float4 xn0, xn1;
    if (kb + 1 < 16) {            // issue next X loads + W gll (fly over MFMA)
      xn0 = *reinterpret_cast<const float4*>(Xsrc + (kb + 1) * 64);
      xn1 = *reinterpret_cast<const float4*>(Xsrc + (kb + 1) * 64 + 4);
      stageW(buf ^ 1, kb + 1);
    }
    // A-fragment (bf16) from swizzled Xl
    const char* xp = (const char*)&Xl[buf][0] + rr * 128;
    bf16x8 a0 = *reinterpret_cast<const bf16x8*>(xp + ((l4       ^ rs7) << 4));
    bf16x8 a1 = *reinterpret_cast<const bf16x8*>(xp + (((4 + l4) ^ rs7) << 4));
    #pragma unroll
    for (int i = 0; i < 6; ++i) {
      const int wrow = nh * 96 + i * 16 + l15;
      const char* wp = (const char*)&Wl[buf][0] + wrow * 128;
      bf16x8 b0 = *reinterpret_cast<const bf16x8*>(wp + ((l4       ^ (wrow & 7)) << 4));
      bf16x8 b1 = *reinterpret_cast<const bf16x8*>(wp + (((4 + l4) ^ (wrow & 7)) << 4));
      acc[i] = __builtin_amdgcn_mfma_f32_16x16x32_bf16(a0, b0, acc[i], 0, 0, 0);
      acc[i] = __builtin_amdgcn_mfma_f32_16x16x32_bf16(a1, b1, acc[i], 0, 0, 0);
    }
    if (kb + 1 < 16) {
      writeX(buf ^ 1, xn0, xn1);  // cvt+write after compute (T14 split)
      __syncthreads();            // drains W gll + X ds_write
    }
  }

  #pragma unroll
  for (int i = 0; i < 6; ++i) {
    int j   = nh * 96 + i * 16 + l15;   // global output col (0..191)
    int mr0 = m0 + mt * 16 + l4 * 4;
    if (j < 64) {
      #pragma unroll
      for (int r = 0; r < 4; ++r)
        Kr[(size_t)(mr0 + r) * 64 + j] = f2bf(acc[i][r] + bk[j]);
    } else if (j < 128) {
      int jq = j - 64;
      #pragma unroll
      for (int r = 0; r < 4; ++r)
        Qs[(size_t)(mr0 + r) * 64 + jq] = f2bf((acc[i][r] + bq[jq]) * QSCALE);
    } else {
      int h = j - 128;
      int bb = mr0 >> 12, t0 = mr0 & 4095;
      ushort4 o;
      o.x = f2bf(acc[i][0] + bv[h]); o.y = f2bf(acc[i][1] + bv[h]);
      o.z = f2bf(acc[i][2] + bv[h]); o.w = f2bf(acc[i][3] + bv[h]);
      *reinterpret_cast<ushort4*>(&Vt[((size_t)(bb * 64 + h)) * 4096 + t0]) = o;
    }
  }
}

// ---- attn8: paired q-tiles, 8 waves, kv-split-8, no in-loop barriers --
__global__ __launch_bounds__(512) void attn8_kernel(
    const unsigned short* __restrict__ Qs,
    const unsigned short* __restrict__ Kr,
    const unsigned short* __restrict__ Vt,
    float* __restrict__ out) {
  __shared__ __align__(16) char smem[98304];   // 96KB: 8 waves x 12KB
  const int tid = threadIdx.x;
  const int w   = tid >> 6;            // 0..7: kv residue class
  const int ln  = tid & 63;
  const int l15 = ln & 15;
  const int l4  = ln >> 4;
  const int bid = blockIdx.x;          // 0..255
  const int pr  = bid >> 2;            // 0..63: q-tile pair index
  const int b   = bid & 3;             // batch pinned per XCD
  const f32x4 zero4 = {0.f, 0.f, 0.f, 0.f};

  char* Kl = smem + w * 12288;         // 2 x 4KB K dbuf
  char* Vl = Kl + 8192;                // 4KB V

  const int kLane = (ln >> 3) * 128 + ((ln & 7) ^ (ln >> 3)) * 16;
  const int vLane = (ln >> 2) * 8192 + (((ln & 3) ^ ((ln >> 3) & 3))) * 16;
  const char* Kbase = (const char*)Kr + (size_t)b * 4096 * 128;
  const char* Vbase = (const char*)Vt + (size_t)b * 64 * 8192;

  auto phase = [&](int qt, bool entryBar) {
    if (entryBar) __syncthreads();     // protect staging LDS vs prior merge
    const int qbase  = qt * 32;
    const int ntiles = qt + 1;         // 32-wide kv tiles

    const unsigned short* Q0 = Qs + ((size_t)b * 4096 + qbase + l15) * 64;
    const bf16x8 qa0 = *reinterpret_cast<const bf16x8*>(Q0 + l4 * 8);
    const bf16x8 qa1 = *reinterpret_cast<const bf16x8*>(Q0 + 32 + l4 * 8);
    const bf16x8 qb0 = *reinterpret_cast<const bf16x8*>(Q0 + 1024 + l4 * 8);
    const bf16x8 qb1 = *reinterpret_cast<const bf16x8*>(Q0 + 1024 + 32 + l4 * 8);

    f32x4 accA[4], accB[4];
    #pragma unroll
    for (int i = 0; i < 4; ++i) { accA[i] = zero4; accB[i] = zero4; }
    float mA = -1e30f, lA = 0.f, mB = -1e30f, lB = 0.f;

    auto stageK = [&](int buf, int t) {
      const char* src = Kbase + (size_t)t * 4096;
      char* dst = Kl + buf * 4096;
      #pragma unroll
      for (int c = 0; c < 4; ++c)
        gl_lds16(src + c * 1024 + kLane, dst + c * 1024 + ln * 16);
    };
    auto stageV = [&](int t) {
      const char* src = Vbase + (size_t)t * 64;
      #pragma unroll
      for (int c = 0; c < 4; ++c)
        gl_lds16(src + (size_t)c * 16 * 8192 + vLane, Vl + c * 1024 + ln * 16);
    };

    int cur = 0;
    if (w < ntiles) stageK(0, w);

    for (int t = w; t < ntiles; t += 8) {
      stageV(t);
      const bool hn = (t + 8 < ntiles);
      if (hn) stageK(cur ^ 1, t + 8);

      if (hn) asm volatile("s_waitcnt vmcnt(8)" ::: "memory");
      else    asm volatile("s_waitcnt vmcnt(4)" ::: "memory");
      __builtin_amdgcn_sched_barrier(0);

      // S^T = K Q^T : s[nt][r] = S[kv=nt*16+4*l4+r][q=l15]
      f32x4 sA[2], sB[2];
      #pragma unroll
      for (int i = 0; i < 2; ++i) { sA[i] = zero4; sB[i] = zero4; }
      __builtin_amdgcn_s_setprio(1);
      #pragma unroll
      for (int nt = 0; nt < 2; ++nt) {
        const int krow = nt * 16 + l15;
        const unsigned short* kp =
            (const unsigned short*)(Kl + cur * 4096) + krow * 64;
        bf16x8 k0 = *reinterpret_cast<const bf16x8*>(kp + ((l4 ^ (krow & 7)) << 3));
        bf16x8 k1 = *reinterpret_cast<const bf16x8*>(kp + (((l4 + 4) ^ (krow & 7)) << 3));
        sA[nt] = __builtin_amdgcn_mfma_f32_16x16x32_bf16(k0, qa0, sA[nt], 0, 0, 0);
        sA[nt] = __builtin_amdgcn_mfma_f32_16x16x32_bf16(k1, qa1, sA[nt], 0, 0, 0);
        sB[nt] = __builtin_amdgcn_mfma_f32_16x16x32_bf16(k0, qb0, sB[nt], 0, 0, 0);
        sB[nt] = __builtin_amdgcn_mfma_f32_16x16x32_bf16(k1, qb1, sB[nt], 0, 0, 0);
      }
      __builtin_amdgcn_s_setprio(0);

      if (t == ntiles - 1) {  // diagonal tile
        const int qm = qbase + l15 - t * 32;
        #pragma unroll
        for (int nt = 0; nt < 2; ++nt)
          #pragma unroll
          for (int r = 0; r < 4; ++r) {
            int kvl = nt * 16 + 4 * l4 + r;
            if (kvl > qm)      sA[nt][r] = -1e30f;
            if (kvl > qm + 16) sB[nt][r] = -1e30f;
          }
      }

      bf16x4 paA[2], paB[2];
      {
        float x0 = fmaxf(fmaxf(sA[0][0], sA[0][1]), fmaxf(sA[0][2], sA[0][3]));
        float x1 = fmaxf(fmaxf(sA[1][0], sA[1][1]), fmaxf(sA[1][2], sA[1][3]));
        float xm = fmaxf(x0, x1);
        xm = fmaxf(xm, __shfl_xor(xm, 16));
        xm = fmaxf(xm, __shfl_xor(xm, 32));
        float mn = fmaxf(mA, xm);
        float cc = fexp2(mA - mn);
        mA = mn; lA *= cc;
        #pragma unroll
        for (int ht = 0; ht < 4; ++ht)
          #pragma unroll
          for (int r = 0; r < 4; ++r) accA[ht][r] *= cc;
        float sum = 0.f;
        #pragma unroll
        for (int nt = 0; nt < 2; ++nt) {
          #pragma unroll
          for (int r = 0; r < 4; ++r) {
            float p = fexp2(sA[nt][r] - mA);
            sA[nt][r] = p;
            paA[nt][r] = (short)f2bf(p);
          }
          sum += (sA[nt][0] + sA[nt][1]) + (sA[nt][2] + sA[nt][3]);
        }
        sum += __shfl_xor(sum, 16);
        sum += __shfl_xor(sum, 32);
        lA += sum;
      }
      {
        float x0 = fmaxf(fmaxf(sB[0][0], sB[0][1]), fmaxf(sB[0][2], sB[0][3]));
        float x1 = fmaxf(fmaxf(sB[1][0], sB[1][1]), fmaxf(sB[1][2], sB[1][3]));
        float xm = fmaxf(x0, x1);
        xm = fmaxf(xm, __shfl_xor(xm, 16));
        xm = fmaxf(xm, __shfl_xor(xm, 32));
        float mn = fmaxf(mB, xm);
        float cc = fexp2(mB - mn);
        mB = mn; lB *= cc;
        #pragma unroll
        for (int ht = 0; ht < 4; ++ht)
          #pragma unroll
          for (int r = 0; r < 4; ++r) accB[ht][r] *= cc;
        float sum = 0.f;
        #pragma unroll
        for (int nt = 0; nt < 2; ++nt) {
          #pragma unroll
          for (int r = 0; r < 4; ++r) {
            float p = fexp2(sB[nt][r] - mB);
            sB[nt][r] = p;
            paB[nt][r] = (short)f2bf(p);
          }
          sum += (sB[nt][0] + sB[nt][1]) + (sB[nt][2] + sB[nt][3]);
        }
        sum += __shfl_xor(sum, 16);
        sum += __shfl_xor(sum, 32);
        lB += sum;
      }

      if (hn) asm volatile("s_waitcnt vmcnt(4)" ::: "memory");
      else    asm volatile("s_waitcnt vmcnt(0)" ::: "memory");
      __builtin_amdgcn_sched_barrier(0);

      // O^T += V^T P^T
      __builtin_amdgcn_s_setprio(1);
      #pragma unroll
      for (int nt = 0; nt < 2; ++nt) {
        #pragma unroll
        for (int ht = 0; ht < 4; ++ht) {
          const int vrow = ht * 16 + l15;
          const int g16 = (nt * 2 + (l4 >> 1)) ^ ((vrow >> 1) & 3);
          const char* vp = Vl + vrow * 64 + (g16 << 4) + ((l4 & 1) << 3);
          bf16x4 vf = *reinterpret_cast<const bf16x4*>(vp);
          accA[ht] = mfma16(vf, paA[nt], accA[ht]);
          accB[ht] = mfma16(vf, paB[nt], accB[ht]);
        }
      }
      __builtin_amdgcn_s_setprio(0);
      cur ^= 1;
    }

    // ---- exact 8-way merge, distributed across all 512 threads -------
    __syncthreads();
    float* MO = (float*)smem;                   // [8][2][16][68] = 68KB
    float* ML = (float*)(smem + 8 * 2 * 16 * 68 * 4);  // [8][2][2][16]
    #pragma unroll
    for (int ht = 0; ht < 4; ++ht) {
      *reinterpret_cast<f32x4*>(&MO[((w * 2 + 0) * 16 + l15) * 68 + ht * 16 + 4 * l4]) = accA[ht];
      *reinterpret_cast<f32x4*>(&MO[((w * 2 + 1) * 16 + l15) * 68 + ht * 16 + 4 * l4]) = accB[ht];
    }
    if (l4 == 0) {
      ML[((w * 2 + 0) * 2 + 0) * 16 + l15] = mA;
      ML[((w * 2 + 0) * 2 + 1) * 16 + l15] = lA;
      ML[((w * 2 + 1) * 2 + 0) * 16 + l15] = mB;
      ML[((w * 2 + 1) * 2 + 1) * 16 + l15] = lB;
    }
    __syncthreads();
    {
      const int hf = tid >> 8;        // 0..1 (q-half)
      const int q  = (tid >> 4) & 15;
      const int hq = tid & 15;        // h-quad
      float mv[8], lv[8];
      float mM = -1e30f;
      #pragma unroll
      for (int p = 0; p < 8; ++p) {
        mv[p] = ML[((p * 2 + hf) * 2 + 0) * 16 + q];
        lv[p] = ML[((p * 2 + hf) * 2 + 1) * 16 + q];
        mM = fmaxf(mM, mv[p]);
      }
      float lT = 0.f, a[8];
      #pragma unroll
      for (int p = 0; p < 8; ++p) { a[p] = fexp2(mv[p] - mM); lT += lv[p] * a[p]; }
      float linv = 1.0f / lT;
      f32x4 o = zero4;
      #pragma unroll
      for (int p = 0; p < 8; ++p) {
        f32x4 v = *reinterpret_cast<const f32x4*>(
            &MO[((p * 2 + hf) * 16 + q) * 68 + hq * 4]);
        o[0] += v[0] * a[p]; o[1] += v[1] * a[p];
        o[2] += v[2] * a[p]; o[3] += v[3] * a[p];
      }
      float4 ov;
      ov.x = o[0] * linv; ov.y = o[1] * linv;
      ov.z = o[2] * linv; ov.w = o[3] * linv;
      *reinterpret_cast<float4*>(
          out + ((size_t)b * 4096 + qbase + hf * 16 + q) * 64 + hq * 4) = ov;
    }
  };

  phase(127 - pr, false);   // big q-tile first
  phase(pr, true);          // complement: total work ~equal for all blocks
}

// ---- Plan-B fallback (ws too small): proj no-Q + attn recompute-Q -----
template <bool WRITE_Q>
__global__ __launch_bounds__(256) void proj_kernel(
    const float* __restrict__ X,  const float* __restrict__ Wk,
    const float* __restrict__ Wq, const float* __restrict__ Wv,
    const float* __restrict__ bk, const float* __restrict__ bq,
    const float* __restrict__ bv, unsigned short* __restrict__ Kr,
    unsigned short* __restrict__ Qs, unsigned short* __restrict__ Vt) {
  constexpr int NT = WRITE_Q ? 12 : 8;
  constexpr int NC = NT / 4;
  __shared__ __align__(16) unsigned short Xl[64 * 72];
  __shared__ __align__(16) unsigned short Wl[NT * 16 * 72];
  const int tid = threadIdx.x;
  const int m0  = blockIdx.x * 64;
  const int w   = tid >> 6;
  const int ln  = tid & 63;
  const int l15 = ln & 15;
  const int l4  = ln >> 4;
  const f32x4 zero4 = {0.f, 0.f, 0.f, 0.f};
  f32x4 acc[NT];
  #pragma unroll
  for (int i = 0; i < NT; ++i) acc[i] = zero4;
  const int wn = tid & 63;
  const int wk = (tid >> 6) * 16;
  for (int kb = 0; kb < 16; ++kb) {
    __syncthreads();
    #pragma unroll
    for (int p = 0; p < 4; ++p) {
      int chunk = tid + p * 256;
      int r = chunk >> 4, c4 = chunk & 15;
      const float4 xv = *reinterpret_cast<const float4*>(
          X + (size_t)(m0 + r) * 1024 + kb * 64 + c4 * 4);
      bf16x4 o;
      o[0] = (short)f2bf(xv.x); o[1] = (short)f2bf(xv.y);
      o[2] = (short)f2bf(xv.z); o[3] = (short)f2bf(xv.w);
      *reinterpret_cast<bf16x4*>(&Xl[r * 72 + c4 * 4]) = o;
    }
    #pragma unroll
    for (int c = 0; c < NC; ++c) {
      const float* Wsrc = (c == 0) ? Wk : ((WRITE_Q && c == 1) ? Wq : Wv);
      bf16x8 w0, w1;
      #pragma unroll
      for (int j = 0; j < 8; ++j)
        w0[j] = (short)f2bf(Wsrc[(size_t)(kb * 64 + wk + j) * 64 + wn]);
      #pragma unroll
      for (int j = 0; j < 8; ++j)
        w1[j] = (short)f2bf(Wsrc[(size_t)(kb * 64 + wk + 8 + j) * 64 + wn]);
      *reinterpret_cast<bf16x8*>(&Wl[(c * 64 + wn) * 72 + wk])     = w0;
      *reinterpret_cast<bf16x8*>(&Wl[(c * 64 + wn) * 72 + wk + 8]) = w1;
    }
    __syncthreads();
    bf16x8 a0 = *reinterpret_cast<const bf16x8*>(&Xl[(w * 16 + l15) * 72 + l4 * 8]);
    bf16x8 a1 = *reinterpret_cast<const bf16x8*>(&Xl[(w * 16 + l15) * 72 + 32 + l4 * 8]);
    #pragma unroll
    for (int nt = 0; nt < NT; ++nt) {
      bf16x8 b0 = *reinterpret_cast<const bf16x8*>(&Wl[(nt * 16 + l15) * 72 + l4 * 8]);
      bf16x8 b1 = *reinterpret_cast<const bf16x8*>(&Wl[(nt * 16 + l15) * 72 + 32 + l4 * 8]);
      acc[nt] = __builtin_amdgcn_mfma_f32_16x16x32_bf16(a0, b0, acc[nt], 0, 0, 0);
      acc[nt] = __builtin_amdgcn_mfma_f32_16x16x32_bf16(a1, b1, acc[nt], 0, 0, 0);
    }
  }
  #pragma unroll
  for (int nt = 0; nt < NT; ++nt) {
    int j = nt * 16 + l15;
    #pragma unroll
    for (int r = 0; r < 4; ++r) {
      int m = m0 + w * 16 + l4 * 4 + r;
      float v = acc[nt][r];
      if (nt < 4) {
        Kr[(size_t)m * 64 + j] = f2bf(v + bk[j]);
      } else if (WRITE_Q && nt < 8) {
        Qs[(size_t)m * 64 + (j - 64)] = f2bf((v + bq[j - 64]) * QSCALE);
      } else {
        int h = j - (WRITE_Q ? 128 : 64);
        int bb = m >> 12, t = m & 4095;
        Vt[((size_t)(bb * 64 + h)) * 4096 + t] = f2bf(v + bv[h]);
      }
    }
  }
}

__global__ __launch_bounds__(256) void attnB_kernel(
    const unsigned short* __restrict__ Kr,
    const unsigned short* __restrict__ Vt,
    const float* __restrict__ X, const float* __restrict__ Wq,
    const float* __restrict__ bq, float* __restrict__ out) {
  __shared__ __align__(16) unsigned short Kl[64 * 72];
  __shared__ __align__(16) unsigned short Vl[64 * 72];
  __shared__ __align__(16) unsigned short Pl[4 * 16 * 72];
  const int tid = threadIdx.x;
  const int w   = tid >> 6;
  const int ln  = tid & 63;
  const int l15 = ln & 15;
  const int l4  = ln >> 4;
  const int b   = blockIdx.y;
  const int q0  = blockIdx.x * 64;
  const int qrow = q0 + w * 16;
  const f32x4 zero4 = {0.f, 0.f, 0.f, 0.f};
  unsigned short* Pw = &Pl[w * 16 * 72];
  f32x4 accq[4];
  #pragma unroll
  for (int i = 0; i < 4; ++i) accq[i] = zero4;
  const int wn = tid & 63;
  const int wk = (tid >> 6) * 16;
  for (int kb = 0; kb < 16; ++kb) {
    __syncthreads();
    #pragma unroll
    for (int p = 0; p < 4; ++p) {
      int chunk = tid + p * 256;
      int r = chunk >> 4, c4 = chunk & 15;
      const float4 xv = *reinterpret_cast<const float4*>(
          X + ((size_t)b * 4096 + q0 + r) * 1024 + kb * 64 + c4 * 4);
      bf16x4 o;
      o[0] = (short)f2bf(xv.x); o[1] = (short)f2bf(xv.y);
      o[2] = (short)f2bf(xv.z); o[3] = (short)f2bf(xv.w);
      *reinterpret_cast<bf16x4*>(&Kl[r * 72 + c4 * 4]) = o;
    }
    bf16x8 w0, w1;
    #pragma unroll
    for (int j = 0; j < 8; ++j)
      w0[j] = (short)f2bf(Wq[(size_t)(kb * 64 + wk + j) * 64 + wn]);
    #pragma unroll
    for (int j = 0; j < 8; ++j)
      w1[j] = (short)f2bf(Wq[(size_t)(kb * 64 + wk + 8 + j) * 64 + wn]);
    *reinterpret_cast<bf16x8*>(&Vl[wn * 72 + wk])     = w0;
    *reinterpret_cast<bf16x8*>(&Vl[wn * 72 + wk + 8]) = w1;
    __syncthreads();
    bf16x8 a0 = *reinterpret_cast<const bf16x8*>(&Kl[(w * 16 + l15) * 72 + l4 * 8]);
    bf16x8 a1 = *reinterpret_cast<const bf16x8*>(&Kl[(w * 16 + l15) * 72 + 32 + l4 * 8]);
    #pragma unroll
    for (int nt = 0; nt < 4; ++nt) {
      bf16x8 b0 = *reinterpret_cast<const bf16x8*>(&Vl[(nt * 16 + l15) * 72 + l4 * 8]);
      bf16x8 b1 = *reinterpret_cast<const bf16x8*>(&Vl[(nt * 16 + l15) * 72 + 32 + l4 * 8]);
      accq[nt] = __builtin_amdgcn_mfma_f32_16x16x32_bf16(a0, b0, accq[nt], 0, 0, 0);
      accq[nt] = __builtin_amdgcn_mfma_f32_16x16x32_bf16(a1, b1, accq[nt], 0, 0, 0);
    }
  }
  #pragma unroll
  for (int nt = 0; nt < 4; ++nt) {
    int h = nt * 16 + l15;
    #pragma unroll
    for (int r = 0; r < 4; ++r)
      Pw[(l4 * 4 + r) * 72 + h] = f2bf((accq[nt][r] + bq[h]) * 0.125f);
  }
  asm volatile("s_waitcnt lgkmcnt(0)" ::: "memory");
  __builtin_amdgcn_sched_barrier(0);
  bf16x8 qa0 = *reinterpret_cast<const bf16x8*>(&Pw[l15 * 72 + l4 * 8]);
  bf16x8 qa1 = *reinterpret_cast<const bf16x8*>(&Pw[l15 * 72 + 32 + l4 * 8]);
  f32x4 acco[4];
  #pragma unroll
  for (int i = 0; i < 4; ++i) acco[i] = zero4;
  float mrow[4] = {-1e30f, -1e30f, -1e30f, -1e30f};
  float lrow[4] = {0.f, 0.f, 0.f, 0.f};
  const int ktmax = blockIdx.x;
  for (int kt = 0; kt <= ktmax; ++kt) {
    const int kv0 = kt * 64;
    __syncthreads();
    #pragma unroll
    for (int p = 0; p < 2; ++p) {
      int chunk = tid + p * 256;
      int r = chunk >> 3, c8 = chunk & 7;
      *reinterpret_cast<bf16x8*>(&Kl[r * 72 + c8 * 8]) =
          *reinterpret_cast<const bf16x8*>(Kr + ((size_t)b * 4096 + kv0 + r) * 64 + c8 * 8);
      *reinterpret_cast<bf16x8*>(&Vl[r * 72 + c8 * 8]) =
          *reinterpret_cast<const bf16x8*>(Vt + ((size_t)b * 64 + r) * 4096 + kv0 + c8 * 8);
    }
    __syncthreads();
    f32x4 s[4];
    #pragma unroll
    for (int i = 0; i < 4; ++i) s[i] = zero4;
    #pragma unroll
    for (int nt = 0; nt < 4; ++nt) {
      bf16x8 k0 = *reinterpret_cast<const bf16x8*>(&Kl[(nt * 16 + l15) * 72 + l4 * 8]);
      bf16x8 k1 = *reinterpret_cast<const bf16x8*>(&Kl[(nt * 16 + l15) * 72 + 32 + l4 * 8]);
      s[nt] = __builtin_amdgcn_mfma_f32_16x16x32_bf16(qa0, k0, s[nt], 0, 0, 0);
      s[nt] = __builtin_amdgcn_mfma_f32_16x16x32_bf16(qa1, k1, s[nt], 0, 0, 0);
    }
    if (kt == ktmax) {
      #pragma unroll
      for (int nt = 0; nt < 4; ++nt) {
        int kv_g = kv0 + nt * 16 + l15;
        #pragma unroll
        for (int r = 0; r < 4; ++r) {
          int q_g = qrow + l4 * 4 + r;
          if (kv_g > q_g) s[nt][r] = -1e30f;
        }
      }
    }
    #pragma unroll
    for (int r = 0; r < 4; ++r) {
      float t = fmaxf(fmaxf(s[0][r], s[1][r]), fmaxf(s[2][r], s[3][r]));
      t = fmaxf(t, __shfl_xor(t, 1));
      t = fmaxf(t, __shfl_xor(t, 2));
      t = fmaxf(t, __shfl_xor(t, 4));
      t = fmaxf(t, __shfl_xor(t, 8));
      float mnew = fmaxf(mrow[r], t);
      float cc = __expf(mrow[r] - mnew);
      mrow[r] = mnew;
      lrow[r] *= cc;
      acco[0][r] *= cc; acco[1][r] *= cc; acco[2][r] *= cc; acco[3][r] *= cc;
    }
    #pragma unroll
    for (int nt = 0; nt < 4; ++nt) {
      #pragma unroll
      for (int r = 0; r < 4; ++r) {
        float p = __expf(s[nt][r] - mrow[r]);
        s[nt][r] = p;
        Pw[(l4 * 4 + r) * 72 + nt * 16 + l15] = f2bf(p);
      }
    }
    #pragma unroll
    for (int r = 0; r < 4; ++r) {
      float t = s[0][r] + s[1][r] + s[2][r] + s[3][r];
      t += __shfl_xor(t, 1);
      t += __shfl_xor(t, 2);
      t += __shfl_xor(t, 4);
      t += __shfl_xor(t, 8);
      lrow[r] += t;
    }
    asm volatile("s_waitcnt lgkmcnt(0)" ::: "memory");
    __builtin_amdgcn_sched_barrier(0);
    #pragma unroll
    for (int ks = 0; ks < 2; ++ks) {
      bf16x8 pa = *reinterpret_cast<const bf16x8*>(&Pw[l15 * 72 + ks * 32 + l4 * 8]);
      #pragma unroll
      for (int ht = 0; ht < 4; ++ht) {
        bf16x8 vf = *reinterpret_cast<const bf16x8*>(&Vl[(ht * 16 + l15) * 72 + ks * 32 + l4 * 8]);
        acco[ht] = __builtin_amdgcn_mfma_f32_16x16x32_bf16(pa, vf, acco[ht], 0, 0, 0);
      }
    }
  }
  float* ob = out + ((size_t)b * 4096 + qrow) * 64;
  #pragma unroll
  for (int ht = 0; ht < 4; ++ht) {
    #pragma unroll
    for (int r = 0; r < 4; ++r) {
      ob[(l4 * 4 + r) * 64 + ht * 16 + l15] = acco[ht][r] / lrow[r];
    }
  }
}

extern "C" void kernel_launch(void* const* d_in, const int* in_sizes, int n_in,
                              void* d_out, int out_size, void* d_ws, size_t ws_size,
                              hipStream_t stream) {
  const float* X  = (const float*)d_in[0];
  const float* Wk = (const float*)d_in[1];
  const float* bk = (const float*)d_in[2];
  const float* Wq = (const float*)d_in[3];
  const float* bq = (const float*)d_in[4];
  const float* Wv = (const float*)d_in[5];
  const float* bv = (const float*)d_in[6];
  float* out = (float*)d_out;

  char* ws = (char*)d_ws;
  const size_t SZ = 2097152;   // one bf16 [B*T][64] buffer
  const size_t WT = 393216;    // Wt bf16[192][1024]
  unsigned short* Kr = (unsigned short*)(ws);
  unsigned short* Vt = (unsigned short*)(ws + SZ);

  if (ws_size >= 3 * SZ) {
    unsigned short* Qs = (unsigned short*)(ws + 2 * SZ);
    // Wt scratch: ws tail if it fits, else head of d_out (attn8 rewrites
    // all of out afterwards on the same stream -> deterministic).
    unsigned short* Wt = (ws_size >= 3 * SZ + WT)
                             ? (unsigned short*)(ws + 3 * SZ)
                             : (unsigned short*)d_out;
    prep_w_kernel<<<192, 256, 0, stream>>>(Wk, Wq, Wv, Wt);
    proj20_kernel<<<256, 512, 0, stream>>>(X, Wt, bk, bq, bv, Kr, Qs, Vt);
    attn8_kernel<<<256, 512, 0, stream>>>(Qs, Kr, Vt, out);
  } else {
    proj_kernel<false><<<256, 256, 0, stream>>>(X, Wk, Wq, Wv, bk, bq, bv, Kr, nullptr, Vt);
    attnB_kernel<<<dim3(64, 4), 256, 0, stream>>>(Kr, Vt, X, Wq, bq, out);
  }
}

// Round 23
// 57.982 us; speedup vs baseline: 1.0862x; 1.0745x over previous
//
#include <hip/hip_runtime.h>

// AttentionHead: B=4, T=4096, C=1024, H=64, causal softmax(QK^T/8)V
// R23 = R16 verbatim (best measured total: 58.4us). prep_w (one-time W
// transpose) + proj8 (gll-staged X fp32 + W bf16, dbuf, 1 barrier/iter)
// + attn8 (balanced q-tile pairs, 8 waves, kv-split-8, barrier-free).
// Ten proj variants (37-53us) establish ~38us as this shape's plateau;
// locking in the best-measured configuration.

using bf16x8 = __attribute__((ext_vector_type(8))) short;
using bf16x4 = __attribute__((ext_vector_type(4))) short;
using f32x4  = __attribute__((ext_vector_type(4))) float;

#define QSCALE 0.1803368867f  // 0.125 * log2(e): softmax in exp2 domain

__device__ __forceinline__ unsigned short f2bf(float f) {
  union { float f; unsigned int u; } v; v.f = f;
  unsigned int r = v.u + 0x7fffu + ((v.u >> 16) & 1u);  // RNE
  return (unsigned short)(r >> 16);
}

__device__ __forceinline__ float fexp2(float x) {
#if __has_builtin(__builtin_amdgcn_exp2f)
  return __builtin_amdgcn_exp2f(x);
#else
  float r; asm("v_exp_f32 %0, %1" : "=v"(r) : "v"(x)); return r;
#endif
}

__device__ __forceinline__ void gl_lds16(const void* g, void* l) {
  __builtin_amdgcn_global_load_lds(
      (const __attribute__((address_space(1))) void*)g,
      (__attribute__((address_space(3))) void*)l, 16, 0, 0);
}

__device__ __forceinline__ f32x4 mfma16(bf16x4 a, bf16x4 b, f32x4 c) {
#if __has_builtin(__builtin_amdgcn_mfma_f32_16x16x16bf16_1k)
  return __builtin_amdgcn_mfma_f32_16x16x16bf16_1k(a, b, c, 0, 0, 0);
#else
  f32x4 d;
  asm volatile("v_mfma_f32_16x16x16_bf16 %0, %1, %2, %3"
               : "=v"(d) : "v"(a), "v"(b), "v"(c));
  return d;
#endif
}

// ---- prep_w: Wt[j][k] = Wsel[k][j%64] bf16 (one-time, 384KB) ----------
__global__ __launch_bounds__(256) void prep_w_kernel(
    const float* __restrict__ Wk, const float* __restrict__ Wq,
    const float* __restrict__ Wv, unsigned short* __restrict__ Wt) {
  int j = blockIdx.x;  // 0..191: [0,64)=K, [64,128)=Q, [128,192)=V
  const float* src = (j < 64) ? Wk : ((j < 128) ? Wq : Wv);
  int jj = j & 63;
  #pragma unroll
  for (int p = 0; p < 4; ++p) {
    int k = threadIdx.x + p * 256;
    Wt[j * 1024 + k] = f2bf(src[k * 64 + jj]);
  }
}

// ---- proj8: 512 blocks x 512 thr; gll-staged X(fp32)+W(bf16), 1 bar ---
__global__ __launch_bounds__(512) void proj8_kernel(
    const float* __restrict__ X, const unsigned short* __restrict__ Wt,
    const float* __restrict__ bk, const float* __restrict__ bq,
    const float* __restrict__ bv, unsigned short* __restrict__ Kr,
    unsigned short* __restrict__ Qs, unsigned short* __restrict__ Vt) {
  __shared__ __align__(16) float          Xl[2][32 * 64];   // 16 KB fp32
  __shared__ __align__(16) unsigned short Wl[2][192 * 64];  // 48 KB bf16
  const int tid = threadIdx.x;
  const int m0  = blockIdx.x * 32;
  const int w   = tid >> 6;      // 0..7
  const int mt  = w & 1;         // 16-row half
  const int nh  = w >> 1;        // 48-col quarter
  const int ln  = tid & 63;
  const int l15 = ln & 15;
  const int l4  = ln >> 4;
  const f32x4 zero4 = {0.f, 0.f, 0.f, 0.f};

  // X gll: 1 granule/thread. row r=tid>>4 (0..31), pos c=tid&15 holds
  // source granule c^(r&7)  (both-sides swizzle, rule #21)
  const int xr = tid >> 4, xc = tid & 15;
  const size_t xsrcLane = (size_t)(m0 + xr) * 4096 + ((xc ^ (xr & 7)) << 4);
  // W gll: 3 granules/thread. g=tid+s*512, row=g>>3, pos g&7 holds
  // source granule (g&7)^(row&7). Wt row stride 2048B.
  const char* Xb = (const char*)X;
  const char* Wb = (const char*)Wt;

  f32x4 acc[3];
  #pragma unroll
  for (int i = 0; i < 3; ++i) acc[i] = zero4;

  auto stageX = [&](int buf, int kb) {
    gl_lds16(Xb + xsrcLane + kb * 256, (char*)&Xl[buf][0] + tid * 16);
  };
  auto stageW = [&](int buf, int kb) {
    #pragma unroll
    for (int s = 0; s < 3; ++s) {
      int g = tid + s * 512;
      int row = g >> 3, gc = g & 7;
      gl_lds16(Wb + (size_t)row * 2048 + kb * 128 + ((gc ^ (row & 7)) << 4),
               (char*)&Wl[buf][0] + g * 16);
    }
  };

  stageX(0, 0);
  stageW(0, 0);
  asm volatile("s_waitcnt vmcnt(0)" ::: "memory");
  __syncthreads();

  const int rr = mt * 16 + l15;           // X fragment row
  const int rs7 = rr & 7;
  for (int kb = 0; kb < 16; ++kb) {
    const int buf = kb & 1;
    if (kb + 1 < 16) {                    // stage next tiles (fly over MFMA)
      stageX(buf ^ 1, kb + 1);
      stageW(buf ^ 1, kb + 1);
    }
    // A-fragments: read fp32 from swizzled Xl, convert to bf16
    const float* xp = &Xl[buf][0] + rr * 64;
    f32x4 xa0 = *reinterpret_cast<const f32x4*>(xp + (((2 * l4)     ^ rs7) << 2));
    f32x4 xa1 = *reinterpret_cast<const f32x4*>(xp + (((2 * l4 + 1) ^ rs7) << 2));
    f32x4 xb0 = *reinterpret_cast<const f32x4*>(xp + (((8 + 2 * l4) ^ rs7) << 2));
    f32x4 xb1 = *reinterpret_cast<const f32x4*>(xp + (((9 + 2 * l4) ^ rs7) << 2));
    bf16x8 a0, a1;
    #pragma unroll
    for (int i = 0; i < 4; ++i) {
      a0[i] = (short)f2bf(xa0[i]); a0[4 + i] = (short)f2bf(xa1[i]);
      a1[i] = (short)f2bf(xb0[i]); a1[4 + i] = (short)f2bf(xb1[i]);
    }
    #pragma unroll
    for (int i = 0; i < 3; ++i) {
      const int row = nh * 48 + i * 16 + l15;
      const unsigned short* wp = &Wl[buf][0] + row * 64;
      bf16x8 b0 = *reinterpret_cast<const bf16x8*>(wp + ((l4       ^ (row & 7)) << 3));
      bf16x8 b1 = *reinterpret_cast<const bf16x8*>(wp + (((4 + l4) ^ (row & 7)) << 3));
      acc[i] = __builtin_amdgcn_mfma_f32_16x16x32_bf16(a0, b0, acc[i], 0, 0, 0);
      acc[i] = __builtin_amdgcn_mfma_f32_16x16x32_bf16(a1, b1, acc[i], 0, 0, 0);
    }
    if (kb + 1 < 16) __syncthreads();     // drains in-flight gll (full-phase)
  }

  #pragma unroll
  for (int i = 0; i < 3; ++i) {
    int j = nh * 48 + i * 16 + l15;
    int mr0 = m0 + mt * 16 + l4 * 4;
    if (j < 64) {
      #pragma unroll
      for (int r = 0; r < 4; ++r)
        Kr[(size_t)(mr0 + r) * 64 + j] = f2bf(acc[i][r] + bk[j]);
    } else if (j < 128) {
      int jq = j - 64;
      #pragma unroll
      for (int r = 0; r < 4; ++r)
        Qs[(size_t)(mr0 + r) * 64 + jq] = f2bf((acc[i][r] + bq[jq]) * QSCALE);
    } else {
      int h = j - 128;
      int bb = mr0 >> 12, t0 = mr0 & 4095;
      ushort4 o;
      o.x = f2bf(acc[i][0] + bv[h]); o.y = f2bf(acc[i][1] + bv[h]);
      o.z = f2bf(acc[i][2] + bv[h]); o.w = f2bf(acc[i][3] + bv[h]);
      *reinterpret_cast<ushort4*>(&Vt[((size_t)(bb * 64 + h)) * 4096 + t0]) = o;
    }
  }
}

// ---- attn8: paired q-tiles, 8 waves, kv-split-8, no in-loop barriers --
__global__ __launch_bounds__(512) void attn8_kernel(
    const unsigned short* __restrict__ Qs,
    const unsigned short* __restrict__ Kr,
    const unsigned short* __restrict__ Vt,
    float* __restrict__ out) {
  __shared__ __align__(16) char smem[98304];   // 96KB: 8 waves x 12KB
  const int tid = threadIdx.x;
  const int w   = tid >> 6;            // 0..7: kv residue class
  const int ln  = tid & 63;
  const int l15 = ln & 15;
  const int l4  = ln >> 4;
  const int bid = blockIdx.x;          // 0..255
  const int pr  = bid >> 2;            // 0..63: q-tile pair index
  const int b   = bid & 3;             // batch pinned per XCD
  const f32x4 zero4 = {0.f, 0.f, 0.f, 0.f};

  char* Kl = smem + w * 12288;         // 2 x 4KB K dbuf
  char* Vl = Kl + 8192;                // 4KB V

  const int kLane = (ln >> 3) * 128 + ((ln & 7) ^ (ln >> 3)) * 16;
  const int vLane = (ln >> 2) * 8192 + (((ln & 3) ^ ((ln >> 3) & 3))) * 16;
  const char* Kbase = (const char*)Kr + (size_t)b * 4096 * 128;
  const char* Vbase = (const char*)Vt + (size_t)b * 64 * 8192;

  auto phase = [&](int qt, bool entryBar) {
    if (entryBar) __syncthreads();     // protect staging LDS vs prior merge
    const int qbase  = qt * 32;
    const int ntiles = qt + 1;         // 32-wide kv tiles

    const unsigned short* Q0 = Qs + ((size_t)b * 4096 + qbase + l15) * 64;
    const bf16x8 qa0 = *reinterpret_cast<const bf16x8*>(Q0 + l4 * 8);
    const bf16x8 qa1 = *reinterpret_cast<const bf16x8*>(Q0 + 32 + l4 * 8);
    const bf16x8 qb0 = *reinterpret_cast<const bf16x8*>(Q0 + 1024 + l4 * 8);
    const bf16x8 qb1 = *reinterpret_cast<const bf16x8*>(Q0 + 1024 + 32 + l4 * 8);

    f32x4 accA[4], accB[4];
    #pragma unroll
    for (int i = 0; i < 4; ++i) { accA[i] = zero4; accB[i] = zero4; }
    float mA = -1e30f, lA = 0.f, mB = -1e30f, lB = 0.f;

    auto stageK = [&](int buf, int t) {
      const char* src = Kbase + (size_t)t * 4096;
      char* dst = Kl + buf * 4096;
      #pragma unroll
      for (int c = 0; c < 4; ++c)
        gl_lds16(src + c * 1024 + kLane, dst + c * 1024 + ln * 16);
    };
    auto stageV = [&](int t) {
      const char* src = Vbase + (size_t)t * 64;
      #pragma unroll
      for (int c = 0; c < 4; ++c)
        gl_lds16(src + (size_t)c * 16 * 8192 + vLane, Vl + c * 1024 + ln * 16);
    };

    int cur = 0;
    if (w < ntiles) stageK(0, w);

    for (int t = w; t < ntiles; t += 8) {
      stageV(t);
      const bool hn = (t + 8 < ntiles);
      if (hn) stageK(cur ^ 1, t + 8);

      if (hn) asm volatile("s_waitcnt vmcnt(8)" ::: "memory");
      else    asm volatile("s_waitcnt vmcnt(4)" ::: "memory");
      __builtin_amdgcn_sched_barrier(0);

      // S^T = K Q^T : s[nt][r] = S[kv=nt*16+4*l4+r][q=l15]
      f32x4 sA[2], sB[2];
      #pragma unroll
      for (int i = 0; i < 2; ++i) { sA[i] = zero4; sB[i] = zero4; }
      __builtin_amdgcn_s_setprio(1);
      #pragma unroll
      for (int nt = 0; nt < 2; ++nt) {
        const int krow = nt * 16 + l15;
        const unsigned short* kp =
            (const unsigned short*)(Kl + cur * 4096) + krow * 64;
        bf16x8 k0 = *reinterpret_cast<const bf16x8*>(kp + ((l4 ^ (krow & 7)) << 3));
        bf16x8 k1 = *reinterpret_cast<const bf16x8*>(kp + (((l4 + 4) ^ (krow & 7)) << 3));
        sA[nt] = __builtin_amdgcn_mfma_f32_16x16x32_bf16(k0, qa0, sA[nt], 0, 0, 0);
        sA[nt] = __builtin_amdgcn_mfma_f32_16x16x32_bf16(k1, qa1, sA[nt], 0, 0, 0);
        sB[nt] = __builtin_amdgcn_mfma_f32_16x16x32_bf16(k0, qb0, sB[nt], 0, 0, 0);
        sB[nt] = __builtin_amdgcn_mfma_f32_16x16x32_bf16(k1, qb1, sB[nt], 0, 0, 0);
      }
      __builtin_amdgcn_s_setprio(0);

      if (t == ntiles - 1) {  // diagonal tile
        const int qm = qbase + l15 - t * 32;
        #pragma unroll
        for (int nt = 0; nt < 2; ++nt)
          #pragma unroll
          for (int r = 0; r < 4; ++r) {
            int kvl = nt * 16 + 4 * l4 + r;
            if (kvl > qm)      sA[nt][r] = -1e30f;
            if (kvl > qm + 16) sB[nt][r] = -1e30f;
          }
      }

      bf16x4 paA[2], paB[2];
      {
        float x0 = fmaxf(fmaxf(sA[0][0], sA[0][1]), fmaxf(sA[0][2], sA[0][3]));
        float x1 = fmaxf(fmaxf(sA[1][0], sA[1][1]), fmaxf(sA[1][2], sA[1][3]));
        float xm = fmaxf(x0, x1);
        xm = fmaxf(xm, __shfl_xor(xm, 16));
        xm = fmaxf(xm, __shfl_xor(xm, 32));
        float mn = fmaxf(mA, xm);
        float cc = fexp2(mA - mn);
        mA = mn; lA *= cc;
        #pragma unroll
        for (int ht = 0; ht < 4; ++ht)
          #pragma unroll
          for (int r = 0; r < 4; ++r) accA[ht][r] *= cc;
        float sum = 0.f;
        #pragma unroll
        for (int nt = 0; nt < 2; ++nt) {
          #pragma unroll
          for (int r = 0; r < 4; ++r) {
            float p = fexp2(sA[nt][r] - mA);
            sA[nt][r] = p;
            paA[nt][r] = (short)f2bf(p);
          }
          sum += (sA[nt][0] + sA[nt][1]) + (sA[nt][2] + sA[nt][3]);
        }
        sum += __shfl_xor(sum, 16);
        sum += __shfl_xor(sum, 32);
        lA += sum;
      }
      {
        float x0 = fmaxf(fmaxf(sB[0][0], sB[0][1]), fmaxf(sB[0][2], sB[0][3]));
        float x1 = fmaxf(fmaxf(sB[1][0], sB[1][1]), fmaxf(sB[1][2], sB[1][3]));
        float xm = fmaxf(x0, x1);
        xm = fmaxf(xm, __shfl_xor(xm, 16));
        xm = fmaxf(xm, __shfl_xor(xm, 32));
        float mn = fmaxf(mB, xm);
        float cc = fexp2(mB - mn);
        mB = mn; lB *= cc;
        #pragma unroll
        for (int ht = 0; ht < 4; ++ht)
          #pragma unroll
          for (int r = 0; r < 4; ++r) accB[ht][r] *= cc;
        float sum = 0.f;
        #pragma unroll
        for (int nt = 0; nt < 2; ++nt) {
          #pragma unroll
          for (int r = 0; r < 4; ++r) {
            float p = fexp2(sB[nt][r] - mB);
            sB[nt][r] = p;
            paB[nt][r] = (short)f2bf(p);
          }
          sum += (sB[nt][0] + sB[nt][1]) + (sB[nt][2] + sB[nt][3]);
        }
        sum += __shfl_xor(sum, 16);
        sum += __shfl_xor(sum, 32);
        lB += sum;
      }

      if (hn) asm volatile("s_waitcnt vmcnt(4)" ::: "memory");
      else    asm volatile("s_waitcnt vmcnt(0)" ::: "memory");
      __builtin_amdgcn_sched_barrier(0);

      // O^T += V^T P^T
      __builtin_amdgcn_s_setprio(1);
      #pragma unroll
      for (int nt = 0; nt < 2; ++nt) {
        #pragma unroll
        for (int ht = 0; ht < 4; ++ht) {
          const int vrow = ht * 16 + l15;
          const int g16 = (nt * 2 + (l4 >> 1)) ^ ((vrow >> 1) & 3);
          const char* vp = Vl + vrow * 64 + (g16 << 4) + ((l4 & 1) << 3);
          bf16x4 vf = *reinterpret_cast<const bf16x4*>(vp);
          accA[ht] = mfma16(vf, paA[nt], accA[ht]);
          accB[ht] = mfma16(vf, paB[nt], accB[ht]);
        }
      }
      __builtin_amdgcn_s_setprio(0);
      cur ^= 1;
    }

    // ---- exact 8-way merge, distributed across all 512 threads -------
    __syncthreads();
    float* MO = (float*)smem;                   // [8][2][16][68] = 68KB
    float* ML = (float*)(smem + 8 * 2 * 16 * 68 * 4);  // [8][2][2][16]
    #pragma unroll
    for (int ht = 0; ht < 4; ++ht) {
      *reinterpret_cast<f32x4*>(&MO[((w * 2 + 0) * 16 + l15) * 68 + ht * 16 + 4 * l4]) = accA[ht];
      *reinterpret_cast<f32x4*>(&MO[((w * 2 + 1) * 16 + l15) * 68 + ht * 16 + 4 * l4]) = accB[ht];
    }
    if (l4 == 0) {
      ML[((w * 2 + 0) * 2 + 0) * 16 + l15] = mA;
      ML[((w * 2 + 0) * 2 + 1) * 16 + l15] = lA;
      ML[((w * 2 + 1) * 2 + 0) * 16 + l15] = mB;
      ML[((w * 2 + 1) * 2 + 1) * 16 + l15] = lB;
    }
    __syncthreads();
    {
      const int hf = tid >> 8;        // 0..1 (q-half)
      const int q  = (tid >> 4) & 15;
      const int hq = tid & 15;        // h-quad
      float mv[8], lv[8];
      float mM = -1e30f;
      #pragma unroll
      for (int p = 0; p < 8; ++p) {
        mv[p] = ML[((p * 2 + hf) * 2 + 0) * 16 + q];
        lv[p] = ML[((p * 2 + hf) * 2 + 1) * 16 + q];
        mM = fmaxf(mM, mv[p]);
      }
      float lT = 0.f, a[8];
      #pragma unroll
      for (int p = 0; p < 8; ++p) { a[p] = fexp2(mv[p] - mM); lT += lv[p] * a[p]; }
      float linv = 1.0f / lT;
      f32x4 o = zero4;
      #pragma unroll
      for (int p = 0; p < 8; ++p) {
        f32x4 v = *reinterpret_cast<const f32x4*>(
            &MO[((p * 2 + hf) * 16 + q) * 68 + hq * 4]);
        o[0] += v[0] * a[p]; o[1] += v[1] * a[p];
        o[2] += v[2] * a[p]; o[3] += v[3] * a[p];
      }
      float4 ov;
      ov.x = o[0] * linv; ov.y = o[1] * linv;
      ov.z = o[2] * linv; ov.w = o[3] * linv;
      *reinterpret_cast<float4*>(
          out + ((size_t)b * 4096 + qbase + hf * 16 + q) * 64 + hq * 4) = ov;
    }
  };

  phase(127 - pr, false);   // big q-tile first
  phase(pr, true);          // complement: total work ~equal for all blocks
}

// ---- Plan-B fallback (ws too small): proj no-Q + attn recompute-Q -----
template <bool WRITE_Q>
__global__ __launch_bounds__(256) void proj_kernel(
    const float* __restrict__ X,  const float* __restrict__ Wk,
    const float* __restrict__ Wq, const float* __restrict__ Wv,
    const float* __restrict__ bk, const float* __restrict__ bq,
    const float* __restrict__ bv, unsigned short* __restrict__ Kr,
    unsigned short* __restrict__ Qs, unsigned short* __restrict__ Vt) {
  constexpr int NT = WRITE_Q ? 12 : 8;
  constexpr int NC = NT / 4;
  __shared__ __align__(16) unsigned short Xl[64 * 72];
  __shared__ __align__(16) unsigned short Wl[NT * 16 * 72];
  const int tid = threadIdx.x;
  const int m0  = blockIdx.x * 64;
  const int w   = tid >> 6;
  const int ln  = tid & 63;
  const int l15 = ln & 15;
  const int l4  = ln >> 4;
  const f32x4 zero4 = {0.f, 0.f, 0.f, 0.f};
  f32x4 acc[NT];
  #pragma unroll
  for (int i = 0; i < NT; ++i) acc[i] = zero4;
  const int wn = tid & 63;
  const int wk = (tid >> 6) * 16;
  for (int kb = 0; kb < 16; ++kb) {
    __syncthreads();
    #pragma unroll
    for (int p = 0; p < 4; ++p) {
      int chunk = tid + p * 256;
      int r = chunk >> 4, c4 = chunk & 15;
      const float4 xv = *reinterpret_cast<const float4*>(
          X + (size_t)(m0 + r) * 1024 + kb * 64 + c4 * 4);
      bf16x4 o;
      o[0] = (short)f2bf(xv.x); o[1] = (short)f2bf(xv.y);
      o[2] = (short)f2bf(xv.z); o[3] = (short)f2bf(xv.w);
      *reinterpret_cast<bf16x4*>(&Xl[r * 72 + c4 * 4]) = o;
    }
    #pragma unroll
    for (int c = 0; c < NC; ++c) {
      const float* Wsrc = (c == 0) ? Wk : ((WRITE_Q && c == 1) ? Wq : Wv);
      bf16x8 w0, w1;
      #pragma unroll
      for (int j = 0; j < 8; ++j)
        w0[j] = (short)f2bf(Wsrc[(size_t)(kb * 64 + wk + j) * 64 + wn]);
      #pragma unroll
      for (int j = 0; j < 8; ++j)
        w1[j] = (short)f2bf(Wsrc[(size_t)(kb * 64 + wk + 8 + j) * 64 + wn]);
      *reinterpret_cast<bf16x8*>(&Wl[(c * 64 + wn) * 72 + wk])     = w0;
      *reinterpret_cast<bf16x8*>(&Wl[(c * 64 + wn) * 72 + wk + 8]) = w1;
    }
    __syncthreads();
    bf16x8 a0 = *reinterpret_cast<const bf16x8*>(&Xl[(w * 16 + l15) * 72 + l4 * 8]);
    bf16x8 a1 = *reinterpret_cast<const bf16x8*>(&Xl[(w * 16 + l15) * 72 + 32 + l4 * 8]);
    #pragma unroll
    for (int nt = 0; nt < NT; ++nt) {
      bf16x8 b0 = *reinterpret_cast<const bf16x8*>(&Wl[(nt * 16 + l15) * 72 + l4 * 8]);
      bf16x8 b1 = *reinterpret_cast<const bf16x8*>(&Wl[(nt * 16 + l15) * 72 + 32 + l4 * 8]);
      acc[nt] = __builtin_amdgcn_mfma_f32_16x16x32_bf16(a0, b0, acc[nt], 0, 0, 0);
      acc[nt] = __builtin_amdgcn_mfma_f32_16x16x32_bf16(a1, b1, acc[nt], 0, 0, 0);
    }
  }
  #pragma unroll
  for (int nt = 0; nt < NT; ++nt) {
    int j = nt * 16 + l15;
    #pragma unroll
    for (int r = 0; r < 4; ++r) {
      int m = m0 + w * 16 + l4 * 4 + r;
      float v = acc[nt][r];
      if (nt < 4) {
        Kr[(size_t)m * 64 + j] = f2bf(v + bk[j]);
      } else if (WRITE_Q && nt < 8) {
        Qs[(size_t)m * 64 + (j - 64)] = f2bf((v + bq[j - 64]) * QSCALE);
      } else {
        int h = j - (WRITE_Q ? 128 : 64);
        int bb = m >> 12, t = m & 4095;
        Vt[((size_t)(bb * 64 + h)) * 4096 + t] = f2bf(v + bv[h]);
      }
    }
  }
}

__global__ __launch_bounds__(256) void attnB_kernel(
    const unsigned short* __restrict__ Kr,
    const unsigned short* __restrict__ Vt,
    const float* __restrict__ X, const float* __restrict__ Wq,
    const float* __restrict__ bq, float* __restrict__ out) {
  __shared__ __align__(16) unsigned short Kl[64 * 72];
  __shared__ __align__(16) unsigned short Vl[64 * 72];
  __shared__ __align__(16) unsigned short Pl[4 * 16 * 72];
  const int tid = threadIdx.x;
  const int w   = tid >> 6;
  const int ln  = tid & 63;
  const int l15 = ln & 15;
  const int l4  = ln >> 4;
  const int b   = blockIdx.y;
  const int q0  = blockIdx.x * 64;
  const int qrow = q0 + w * 16;
  const f32x4 zero4 = {0.f, 0.f, 0.f, 0.f};
  unsigned short* Pw = &Pl[w * 16 * 72];
  f32x4 accq[4];
  #pragma unroll
  for (int i = 0; i < 4; ++i) accq[i] = zero4;
  const int wn = tid & 63;
  const int wk = (tid >> 6) * 16;
  for (int kb = 0; kb < 16; ++kb) {
    __syncthreads();
    #pragma unroll
    for (int p = 0; p < 4; ++p) {
      int chunk = tid + p * 256;
      int r = chunk >> 4, c4 = chunk & 15;
      const float4 xv = *reinterpret_cast<const float4*>(
          X + ((size_t)b * 4096 + q0 + r) * 1024 + kb * 64 + c4 * 4);
      bf16x4 o;
      o[0] = (short)f2bf(xv.x); o[1] = (short)f2bf(xv.y);
      o[2] = (short)f2bf(xv.z); o[3] = (short)f2bf(xv.w);
      *reinterpret_cast<bf16x4*>(&Kl[r * 72 + c4 * 4]) = o;
    }
    bf16x8 w0, w1;
    #pragma unroll
    for (int j = 0; j < 8; ++j)
      w0[j] = (short)f2bf(Wq[(size_t)(kb * 64 + wk + j) * 64 + wn]);
    #pragma unroll
    for (int j = 0; j < 8; ++j)
      w1[j] = (short)f2bf(Wq[(size_t)(kb * 64 + wk + 8 + j) * 64 + wn]);
    *reinterpret_cast<bf16x8*>(&Vl[wn * 72 + wk])     = w0;
    *reinterpret_cast<bf16x8*>(&Vl[wn * 72 + wk + 8]) = w1;
    __syncthreads();
    bf16x8 a0 = *reinterpret_cast<const bf16x8*>(&Kl[(w * 16 + l15) * 72 + l4 * 8]);
    bf16x8 a1 = *reinterpret_cast<const bf16x8*>(&Kl[(w * 16 + l15) * 72 + 32 + l4 * 8]);
    #pragma unroll
    for (int nt = 0; nt < 4; ++nt) {
      bf16x8 b0 = *reinterpret_cast<const bf16x8*>(&Vl[(nt * 16 + l15) * 72 + l4 * 8]);
      bf16x8 b1 = *reinterpret_cast<const bf16x8*>(&Vl[(nt * 16 + l15) * 72 + 32 + l4 * 8]);
      accq[nt] = __builtin_amdgcn_mfma_f32_16x16x32_bf16(a0, b0, accq[nt], 0, 0, 0);
      accq[nt] = __builtin_amdgcn_mfma_f32_16x16x32_bf16(a1, b1, accq[nt], 0, 0, 0);
    }
  }
  #pragma unroll
  for (int nt = 0; nt < 4; ++nt) {
    int h = nt * 16 + l15;
    #pragma unroll
    for (int r = 0; r < 4; ++r)
      Pw[(l4 * 4 + r) * 72 + h] = f2bf((accq[nt][r] + bq[h]) * 0.125f);
  }
  asm volatile("s_waitcnt lgkmcnt(0)" ::: "memory");
  __builtin_amdgcn_sched_barrier(0);
  bf16x8 qa0 = *reinterpret_cast<const bf16x8*>(&Pw[l15 * 72 + l4 * 8]);
  bf16x8 qa1 = *reinterpret_cast<const bf16x8*>(&Pw[l15 * 72 + 32 + l4 * 8]);
  f32x4 acco[4];
  #pragma unroll
  for (int i = 0; i < 4; ++i) acco[i] = zero4;
  float mrow[4] = {-1e30f, -1e30f, -1e30f, -1e30f};
  float lrow[4] = {0.f, 0.f, 0.f, 0.f};
  const int ktmax = blockIdx.x;
  for (int kt = 0; kt <= ktmax; ++kt) {
    const int kv0 = kt * 64;
    __syncthreads();
    #pragma unroll
    for (int p = 0; p < 2; ++p) {
      int chunk = tid + p * 256;
      int r = chunk >> 3, c8 = chunk & 7;
      *reinterpret_cast<bf16x8*>(&Kl[r * 72 + c8 * 8]) =
          *reinterpret_cast<const bf16x8*>(Kr + ((size_t)b * 4096 + kv0 + r) * 64 + c8 * 8);
      *reinterpret_cast<bf16x8*>(&Vl[r * 72 + c8 * 8]) =
          *reinterpret_cast<const bf16x8*>(Vt + ((size_t)b * 64 + r) * 4096 + kv0 + c8 * 8);
    }
    __syncthreads();
    f32x4 s[4];
    #pragma unroll
    for (int i = 0; i < 4; ++i) s[i] = zero4;
    #pragma unroll
    for (int nt = 0; nt < 4; ++nt) {
      bf16x8 k0 = *reinterpret_cast<const bf16x8*>(&Kl[(nt * 16 + l15) * 72 + l4 * 8]);
      bf16x8 k1 = *reinterpret_cast<const bf16x8*>(&Kl[(nt * 16 + l15) * 72 + 32 + l4 * 8]);
      s[nt] = __builtin_amdgcn_mfma_f32_16x16x32_bf16(qa0, k0, s[nt], 0, 0, 0);
      s[nt] = __builtin_amdgcn_mfma_f32_16x16x32_bf16(qa1, k1, s[nt], 0, 0, 0);
    }
    if (kt == ktmax) {
      #pragma unroll
      for (int nt = 0; nt < 4; ++nt) {
        int kv_g = kv0 + nt * 16 + l15;
        #pragma unroll
        for (int r = 0; r < 4; ++r) {
          int q_g = qrow + l4 * 4 + r;
          if (kv_g > q_g) s[nt][r] = -1e30f;
        }
      }
    }
    #pragma unroll
    for (int r = 0; r < 4; ++r) {
      float t = fmaxf(fmaxf(s[0][r], s[1][r]), fmaxf(s[2][r], s[3][r]));
      t = fmaxf(t, __shfl_xor(t, 1));
      t = fmaxf(t, __shfl_xor(t, 2));
      t = fmaxf(t, __shfl_xor(t, 4));
      t = fmaxf(t, __shfl_xor(t, 8));
      float mnew = fmaxf(mrow[r], t);
      float cc = __expf(mrow[r] - mnew);
      mrow[r] = mnew;
      lrow[r] *= cc;
      acco[0][r] *= cc; acco[1][r] *= cc; acco[2][r] *= cc; acco[3][r] *= cc;
    }
    #pragma unroll
    for (int nt = 0; nt < 4; ++nt) {
      #pragma unroll
      for (int r = 0; r < 4; ++r) {
        float p = __expf(s[nt][r] - mrow[r]);
        s[nt][r] = p;
        Pw[(l4 * 4 + r) * 72 + nt * 16 + l15] = f2bf(p);
      }
    }
    #pragma unroll
    for (int r = 0; r < 4; ++r) {
      float t = s[0][r] + s[1][r] + s[2][r] + s[3][r];
      t += __shfl_xor(t, 1);
      t += __shfl_xor(t, 2);
      t += __shfl_xor(t, 4);
      t += __shfl_xor(t, 8);
      lrow[r] += t;
    }
    asm volatile("s_waitcnt lgkmcnt(0)" ::: "memory");
    __builtin_amdgcn_sched_barrier(0);
    #pragma unroll
    for (int ks = 0; ks < 2; ++ks) {
      bf16x8 pa = *reinterpret_cast<const bf16x8*>(&Pw[l15 * 72 + ks * 32 + l4 * 8]);
      #pragma unroll
      for (int ht = 0; ht < 4; ++ht) {
        bf16x8 vf = *reinterpret_cast<const bf16x8*>(&Vl[(ht * 16 + l15) * 72 + ks * 32 + l4 * 8]);
        acco[ht] = __builtin_amdgcn_mfma_f32_16x16x32_bf16(pa, vf, acco[ht], 0, 0, 0);
      }
    }
  }
  float* ob = out + ((size_t)b * 4096 + qrow) * 64;
  #pragma unroll
  for (int ht = 0; ht < 4; ++ht) {
    #pragma unroll
    for (int r = 0; r < 4; ++r) {
      ob[(l4 * 4 + r) * 64 + ht * 16 + l15] = acco[ht][r] / lrow[r];
    }
  }
}

extern "C" void kernel_launch(void* const* d_in, const int* in_sizes, int n_in,
                              void* d_out, int out_size, void* d_ws, size_t ws_size,
                              hipStream_t stream) {
  const float* X  = (const float*)d_in[0];
  const float* Wk = (const float*)d_in[1];
  const float* bk = (const float*)d_in[2];
  const float* Wq = (const float*)d_in[3];
  const float* bq = (const float*)d_in[4];
  const float* Wv = (const float*)d_in[5];
  const float* bv = (const float*)d_in[6];
  float* out = (float*)d_out;

  char* ws = (char*)d_ws;
  const size_t SZ = 2097152;   // one bf16 [B*T][64] buffer
  const size_t WT = 393216;    // Wt bf16[192][1024]
  unsigned short* Kr = (unsigned short*)(ws);
  unsigned short* Vt = (unsigned short*)(ws + SZ);

  if (ws_size >= 3 * SZ) {
    unsigned short* Qs = (unsigned short*)(ws + 2 * SZ);
    // Wt scratch: ws tail if it fits, else head of d_out (attn8 rewrites
    // all of out afterwards on the same stream -> deterministic).
    unsigned short* Wt = (ws_size >= 3 * SZ + WT)
                             ? (unsigned short*)(ws + 3 * SZ)
                             : (unsigned short*)d_out;
    prep_w_kernel<<<192, 256, 0, stream>>>(Wk, Wq, Wv, Wt);
    proj8_kernel<<<512, 512, 0, stream>>>(X, Wt, bk, bq, bv, Kr, Qs, Vt);
    attn8_kernel<<<256, 512, 0, stream>>>(Qs, Kr, Vt, out);
  } else {
    proj_kernel<false><<<256, 256, 0, stream>>>(X, Wk, Wq, Wv, bk, bq, bv, Kr, nullptr, Vt);
    attnB_kernel<<<dim3(64, 4), 256, 0, stream>>>(Kr, Vt, X, Wq, bq, out);
  }
}